// Round 20
// baseline (536.889 us; speedup 1.0000x reference)
//
#include <hip/hip_runtime.h>

typedef __attribute__((ext_vector_type(8))) short short8;
typedef __attribute__((ext_vector_type(4))) float f32x4;
typedef __attribute__((ext_vector_type(4))) int int4v;

__device__ __forceinline__ float bf2f(unsigned short u) {
  unsigned int x = ((unsigned int)u) << 16;
  float f;
  __builtin_memcpy(&f, &x, 4);
  return f;
}
__device__ __forceinline__ unsigned short f2bf(float f) {
  unsigned int x;
  __builtin_memcpy(&x, &f, 4);
  unsigned int r = (x + 0x7FFFu + ((x >> 16) & 1u)) >> 16;
  return (unsigned short)r;
}
__device__ __forceinline__ unsigned int cvtpk_bf16(float lo, float hi) {
  unsigned int r;
  asm("v_cvt_pk_bf16_f32 %0, %1, %2" : "=v"(r) : "v"(lo), "v"(hi));
  return r;
}
// hardware exp2: v_exp_f32 computes D = 2^S0
__device__ __forceinline__ float exp2_hw(float x) {
  float r;
  asm("v_exp_f32 %0, %1" : "=v"(r) : "v"(x));
  return r;
}
__device__ __forceinline__ int4v s8_to_i4(short8 v) {
  int4v r;
  __builtin_memcpy(&r, &v, 16);
  return r;
}
__device__ __forceinline__ short8 i4_to_s8(int4v v) {
  short8 r;
  __builtin_memcpy(&r, &v, 16);
  return r;
}
__device__ __forceinline__ short8 ld8_f32(const float* p) {
  f32x4 x = *(const f32x4*)p;
  f32x4 y = *(const f32x4*)(p + 4);
  short8 r;
  r[0] = (short)f2bf(x[0]); r[1] = (short)f2bf(x[1]);
  r[2] = (short)f2bf(x[2]); r[3] = (short)f2bf(x[3]);
  r[4] = (short)f2bf(y[0]); r[5] = (short)f2bf(y[1]);
  r[6] = (short)f2bf(y[2]); r[7] = (short)f2bf(y[3]);
  return r;
}

__device__ __forceinline__ void async16(unsigned short* lds, const unsigned short* g) {
  __builtin_amdgcn_global_load_lds(
      (const __attribute__((address_space(1))) void*)g,
      (__attribute__((address_space(3))) void*)lds, 16, 0, 0);
}

// ---------------------------------------------------------------------------
__global__ void downcast_f2b(const float* __restrict__ in,
                             unsigned short* __restrict__ out, int n8) {
  int i = blockIdx.x * 256 + threadIdx.x;
  if (i >= n8) return;
  *(short8*)(out + (size_t)i * 8) = ld8_f32(in + (size_t)i * 8);
}

// ---------------------------------------------------------------------------
// Vectorized transpose + downcast: in fp32 (R x C) -> out bf16 (C x R).
// ---------------------------------------------------------------------------
__global__ void transpose64_f2b(const float* __restrict__ in,
                                unsigned short* __restrict__ out, int R, int C) {
  alignas(16) __shared__ unsigned short t[64][72];
  const int c0 = blockIdx.x * 64;
  const int r0 = blockIdx.y * 64;
  const int tid = threadIdx.x;
  const int rr = tid >> 4;
  const int cc = (tid & 15) << 2;
#pragma unroll
  for (int i = 0; i < 4; i++) {
    int r = rr + i * 16;
    f32x4 v = *(const f32x4*)(in + (size_t)(r0 + r) * C + c0 + cc);
#pragma unroll
    for (int j = 0; j < 4; j++) t[cc + j][r] = f2bf(v[j]);
  }
  __syncthreads();
  const int seg = tid & 7;
  const int cr = tid >> 3;
#pragma unroll
  for (int i = 0; i < 2; i++) {
    int c = cr + i * 32;
    short8 w = *(const short8*)&t[c][seg * 8];
    *(short8*)(out + (size_t)(c0 + c) * R + r0 + seg * 8) = w;
  }
}

// ---------------------------------------------------------------------------
// GEMM 256x256, BK=64, 8 waves, 8-phase schedule (m201 template). Round-14
// form (validated: conflicts 0, ~1250 TF resident). Used for the O-gemm
// (grid 256 = perfectly packed at 1 block/CU).
// ---------------------------------------------------------------------------
#define MFMA16(AF, B0, B1, N0, N1)                                                   \
  _Pragma("unroll") for (int mi = 0; mi < 8; mi++) {                                 \
    acc[mi][N0] = __builtin_amdgcn_mfma_f32_16x16x32_bf16(AF[mi], B0, acc[mi][N0], 0, 0, 0); \
    acc[mi][N1] = __builtin_amdgcn_mfma_f32_16x16x32_bf16(AF[mi], B1, acc[mi][N1], 0, 0, 0); \
  }

#define STAGE8(BUF, SLOT, BASE, KOFF)                                     \
  do {                                                                    \
    async16(&lds[BUF][SLOT][tid * 8], (BASE) + (KOFF));                   \
    async16(&lds[BUF][SLOT][4096 + tid * 8], (BASE) + Kstep128 + (KOFF)); \
  } while (0)

#define BAR8 asm volatile("s_barrier" ::: "memory")

#define TILE8(CUR, UU, S0, S123, VM)                                                   \
  do {                                                                                 \
    const int kb = (UU)*64;                                                            \
    short8 af[8], b0, b1;                                                              \
    /* ph0 (k0,L) */                                                                   \
    _Pragma("unroll") for (int mi = 0; mi < 8; mi++)                                   \
        af[mi] = *(const short8*)(&lds[CUR][0][(wr * 128 + mi * 16 + fr) * 32 + fragoff]); \
    b0 = *(const short8*)(&lds[CUR][2][(wc * 64 + 0 * 16 + fr) * 32 + fragoff]);       \
    b1 = *(const short8*)(&lds[CUR][2][(wc * 64 + 1 * 16 + fr) * 32 + fragoff]);       \
    if (S0) STAGE8((CUR) ^ 1, 3, Bbase, kb + 96);                                      \
    BAR8;                                                                              \
    __builtin_amdgcn_s_setprio(1);                                                     \
    MFMA16(af, b0, b1, 0, 1);                                                          \
    __builtin_amdgcn_s_setprio(0);                                                     \
    BAR8;                                                                              \
    /* ph1 (k0,R) */                                                                   \
    b0 = *(const short8*)(&lds[CUR][2][(wc * 64 + 2 * 16 + fr) * 32 + fragoff]);       \
    b1 = *(const short8*)(&lds[CUR][2][(wc * 64 + 3 * 16 + fr) * 32 + fragoff]);       \
    if (S123) STAGE8(CUR, 0, Abase, kb + 128);                                         \
    BAR8;                                                                              \
    __builtin_amdgcn_s_setprio(1);                                                     \
    MFMA16(af, b0, b1, 2, 3);                                                          \
    __builtin_amdgcn_s_setprio(0);                                                     \
    BAR8;                                                                              \
    /* ph2 (k1,L) */                                                                   \
    _Pragma("unroll") for (int mi = 0; mi < 8; mi++)                                   \
        af[mi] = *(const short8*)(&lds[CUR][1][(wr * 128 + mi * 16 + fr) * 32 + fragoff]); \
    b0 = *(const short8*)(&lds[CUR][3][(wc * 64 + 0 * 16 + fr) * 32 + fragoff]);       \
    b1 = *(const short8*)(&lds[CUR][3][(wc * 64 + 1 * 16 + fr) * 32 + fragoff]);       \
    if (S123) STAGE8(CUR, 2, Bbase, kb + 128);                                         \
    BAR8;                                                                              \
    __builtin_amdgcn_s_setprio(1);                                                     \
    MFMA16(af, b0, b1, 0, 1);                                                          \
    __builtin_amdgcn_s_setprio(0);                                                     \
    BAR8;                                                                              \
    /* ph3 (k1,R) */                                                                   \
    b0 = *(const short8*)(&lds[CUR][3][(wc * 64 + 2 * 16 + fr) * 32 + fragoff]);       \
    b1 = *(const short8*)(&lds[CUR][3][(wc * 64 + 3 * 16 + fr) * 32 + fragoff]);       \
    if (S123) STAGE8(CUR, 1, Abase, kb + 160);                                         \
    BAR8;                                                                              \
    __builtin_amdgcn_s_setprio(1);                                                     \
    MFMA16(af, b0, b1, 2, 3);                                                          \
    __builtin_amdgcn_s_setprio(0);                                                     \
    if ((VM) == 6) {                                                                   \
      asm volatile("s_waitcnt vmcnt(6)" ::: "memory");                                 \
      __builtin_amdgcn_sched_barrier(0);                                               \
    } else if ((VM) == 0) {                                                            \
      asm volatile("s_waitcnt vmcnt(0)" ::: "memory");                                 \
      __builtin_amdgcn_sched_barrier(0);                                               \
    }                                                                                  \
    BAR8;                                                                              \
  } while (0)

template <int CF32>
__global__ __launch_bounds__(512, 2) void gemm8p(
    const unsigned short* __restrict__ A, const unsigned short* __restrict__ BT,
    void* __restrict__ Cp, int M, int N, int K) {
  alignas(16) __shared__ unsigned short lds[2][4][8192];  // 128 KB
  const int tid = threadIdx.x;
  const int l = tid & 63;
  const int wv = tid >> 6;
  const int wr = wv >> 2, wc = wv & 3;

  const int nwg = gridDim.x * gridDim.y;
  int id = blockIdx.y * gridDim.x + blockIdx.x;
  id = (id & 7) * (nwg >> 3) + (id >> 3);
  const int bm = (id % gridDim.x) * 256;
  const int bn = (id / gridDim.x) * 256;

  const int fr = l & 15, hi = l >> 4;
  const int fragoff = ((hi ^ (((fr >> 3) & 1) << 1)) << 3);
  const int srow = tid >> 2;
  const int scol = (((tid & 3) ^ (((tid >> 5) & 1) << 1)) << 3);
  const unsigned short* Abase = A + (size_t)(bm + srow) * K + scol;
  const unsigned short* Bbase = BT + (size_t)(bn + srow) * K + scol;
  const size_t Kstep128 = (size_t)128 * K;

  f32x4 acc[8][4] = {};
  const int nt = K >> 6;

  STAGE8(0, 0, Abase, 0);
  STAGE8(0, 2, Bbase, 0);
  STAGE8(0, 1, Abase, 32);
  STAGE8(0, 3, Bbase, 32);
  STAGE8(1, 0, Abase, 64);
  STAGE8(1, 2, Bbase, 64);
  STAGE8(1, 1, Abase, 96);
  asm volatile("s_waitcnt vmcnt(6)" ::: "memory");
  __builtin_amdgcn_sched_barrier(0);
  BAR8;

  int U = 0;
  for (; U + 3 < nt; U += 2) {
    TILE8(0, U, 1, 1, 6);
    TILE8(1, U + 1, 1, 1, 6);
  }
  TILE8(0, nt - 2, 1, 0, 0);
  TILE8(1, nt - 1, 0, 0, -1);

  const int er = hi << 2;
#pragma unroll
  for (int mi = 0; mi < 8; mi++) {
#pragma unroll
    for (int ni = 0; ni < 4; ni++) {
      int row = bm + wr * 128 + mi * 16 + er;
      int col = bn + wc * 64 + ni * 16 + fr;
#pragma unroll
      for (int r = 0; r < 4; r++) {
        if constexpr (CF32)
          ((float*)Cp)[(size_t)(row + r) * N + col] = acc[mi][ni][r];
        else
          ((unsigned short*)Cp)[(size_t)(row + r) * N + col] = f2bf(acc[mi][ni][r]);
      }
    }
  }
}

// ---------------------------------------------------------------------------
// GEMM2: 256x128 tile, BK=32, 8 waves, 48 KB LDS -> 2 blocks/CU. For the
// QKV projection: grid 16x48 = 768 blocks = exactly 3 per CU.
// launch_bounds (512,2): round-19's (512,4) coerced a 64-VGPR allocation
// and spilled (FETCH +190 MB). (512,2) lets the allocator land ~120 VGPR;
// <=128 still gives 4 waves/SIMD = 2 blocks/CU naturally.
// ---------------------------------------------------------------------------
__global__ __launch_bounds__(512, 2) void gemm2(
    const unsigned short* __restrict__ A, const unsigned short* __restrict__ BT,
    unsigned short* __restrict__ Cp, int M, int N, int K) {
  alignas(16) __shared__ unsigned short lds[2][12288];  // [A 8192 | B 4096] x2
  const int tid = threadIdx.x;
  const int l = tid & 63;
  const int wv = tid >> 6;
  const int wr = wv >> 2;   // 0..1 (M half, 128 rows)
  const int wc = wv & 3;    // 0..3 (N quarter, 32 cols)

  const int nwg = gridDim.x * gridDim.y;
  int id = blockIdx.y * gridDim.x + blockIdx.x;
  id = (id & 7) * (nwg >> 3) + (id >> 3);
  const int bm = (id % gridDim.x) * 256;
  const int bn = (id / gridDim.x) * 128;

  const int fr = l & 15, hi = l >> 4;
  const int fragoff = ((hi ^ (((fr >> 3) & 1) << 1)) << 3);
  const int srow = tid >> 2;
  const int scol = (((tid & 3) ^ (((tid >> 5) & 1) << 1)) << 3);
  const unsigned short* Abase = A + (size_t)(bm + srow) * K + scol;
  const unsigned short* Bbase = BT + (size_t)(bn + srow) * K + scol;  // srow<128 rows used
  const size_t Kstep128 = (size_t)128 * K;

  f32x4 acc[8][2] = {};
  const int nt = K >> 5;  // 32-wide K tiles

#define G2_STAGE(BUF, KOFF)                                              \
  do {                                                                   \
    async16(&lds[BUF][tid * 8], Abase + (KOFF));                         \
    async16(&lds[BUF][4096 + tid * 8], Abase + Kstep128 + (KOFF));       \
    async16(&lds[BUF][8192 + tid * 8], Bbase + (KOFF));                  \
  } while (0)

  // prologue: stage tiles 0,1
  G2_STAGE(0, 0);
  G2_STAGE(1, 32);
  asm volatile("s_waitcnt vmcnt(3)" ::: "memory");  // tile0's 3 asyncs done
  __builtin_amdgcn_sched_barrier(0);
  BAR8;

  for (int t = 0; t < nt; ++t) {
    const int cur = t & 1;
    short8 a[8], b0, b1;
#pragma unroll
    for (int mi = 0; mi < 8; mi++)
      a[mi] = *(const short8*)(&lds[cur][(wr * 128 + mi * 16 + fr) * 32 + fragoff]);
    b0 = *(const short8*)(&lds[cur][8192 + (wc * 32 + fr) * 32 + fragoff]);
    b1 = *(const short8*)(&lds[cur][8192 + (wc * 32 + 16 + fr) * 32 + fragoff]);
    BAR8;  // all waves done reading buf cur -> safe to restage it
    if (t + 2 < nt) G2_STAGE(cur, (t + 2) * 32);
    __builtin_amdgcn_s_setprio(1);
#pragma unroll
    for (int mi = 0; mi < 8; mi++) {
      acc[mi][0] = __builtin_amdgcn_mfma_f32_16x16x32_bf16(a[mi], b0, acc[mi][0], 0, 0, 0);
      acc[mi][1] = __builtin_amdgcn_mfma_f32_16x16x32_bf16(a[mi], b1, acc[mi][1], 0, 0, 0);
    }
    __builtin_amdgcn_s_setprio(0);
    if (t + 2 < nt)
      asm volatile("s_waitcnt vmcnt(3)" ::: "memory");  // t+1 landed, t+2 in flight
    else
      asm volatile("s_waitcnt vmcnt(0)" ::: "memory");
    __builtin_amdgcn_sched_barrier(0);
    BAR8;  // buf cur^1 (tile t+1) staged & visible to all
  }

  const int er = hi << 2;
#pragma unroll
  for (int mi = 0; mi < 8; mi++) {
#pragma unroll
    for (int ni = 0; ni < 2; ni++) {
      int row = bm + wr * 128 + mi * 16 + er;
      int col = bn + wc * 32 + ni * 16 + fr;
#pragma unroll
      for (int r = 0; r < 4; r++)
        Cp[(size_t)(row + r) * N + col] = f2bf(acc[mi][ni][r]);
    }
  }
#undef G2_STAGE
}

// ---------------------------------------------------------------------------
// Merged RoPE on the QKV buffer (4096 tokens x 6144). Q region scaled by
// qscale (= attscale*log2e); K region unscaled.
// ---------------------------------------------------------------------------
__global__ void rope_qk(unsigned short* __restrict__ qkv,
                        const float* __restrict__ cosb,
                        const float* __restrict__ sinb, float qscale) {
  int gid = blockIdx.x * 256 + threadIdx.x;
  const int isK = gid >= 1048576;
  int g = isK ? gid - 1048576 : gid;
  const int nhs = isK ? 3 : 5;
  const int base = isK ? 4096 : 0;
  const float sc = isK ? 1.0f : qscale;
  int dblk = g & 7;
  int u2 = g >> 3;
  int head = u2 & ((1 << nhs) - 1);
  int token = u2 >> nhs;
  int s = token & 2047;
  int d0 = dblk << 3;
  unsigned short* p0 = qkv + (size_t)token * 6144 + base + (head << 7) + d0;
  unsigned short* p1 = p0 + 64;
  const float* cp = cosb + s * 128 + d0;
  const float* sp = sinb + s * 128 + d0;
  short8 a = *(const short8*)p0;
  short8 bq = *(const short8*)p1;
  f32x4 c0 = *(const f32x4*)cp, c1 = *(const f32x4*)(cp + 4);
  f32x4 s0 = *(const f32x4*)sp, s1 = *(const f32x4*)(sp + 4);
  short8 o0, o1;
#pragma unroll
  for (int j = 0; j < 8; j++) {
    float x0 = bf2f((unsigned short)a[j]);
    float x1 = bf2f((unsigned short)bq[j]);
    float c = (j < 4) ? c0[j & 3] : c1[j & 3];
    float sn = (j < 4) ? s0[j & 3] : s1[j & 3];
    o0[j] = (short)f2bf((x0 * c - x1 * sn) * sc);
    o1[j] = (short)f2bf((x1 * c + x0 * sn) * sc);
  }
  *(short8*)p0 = o0;
  *(short8*)p1 = o1;
}

// ---------------------------------------------------------------------------
// Flash attention (round-18 form, validated): causal, GQA. QBLK=128, KVBLK=64,
// paired scheduling (uniform 34 kv-iters/block, grid 8x32x2), double-buffered
// lK/lV, K staged by global_load_lds direct (swizzled global source).
// ---------------------------------------------------------------------------
#define NEGBIG -30000.0f

__device__ __forceinline__ int vswz(int d) { return (((d >> 3) ^ d) & 7) << 2; }

__device__ __forceinline__ void packV(const short8 vreg[4], int parity,
                                      unsigned int vw[4][4]) {
#pragma unroll
  for (int rep = 0; rep < 4; rep++) {
    int4v own = s8_to_i4(vreg[rep]);
    int4v oth;
#pragma unroll
    for (int q = 0; q < 4; q++) oth[q] = __shfl_xor(own[q], 16);
    unsigned int oA = parity ? (unsigned)own[2] : (unsigned)own[0];
    unsigned int oB = parity ? (unsigned)own[3] : (unsigned)own[1];
    unsigned int tA = parity ? (unsigned)oth[2] : (unsigned)oth[0];
    unsigned int tB = parity ? (unsigned)oth[3] : (unsigned)oth[1];
    unsigned int evA = parity ? tA : oA, odA = parity ? oA : tA;
    unsigned int evB = parity ? tB : oB, odB = parity ? oB : tB;
    vw[rep][0] = (evA & 0xFFFFu) | (odA << 16);
    vw[rep][1] = (evA >> 16) | (odA & 0xFFFF0000u);
    vw[rep][2] = (evB & 0xFFFFu) | (odB << 16);
    vw[rep][3] = (evB >> 16) | (odB & 0xFFFF0000u);
  }
}

__global__ __launch_bounds__(256, 2) void flash_attn(
    const unsigned short* __restrict__ QKV, unsigned short* __restrict__ O) {
  alignas(16) __shared__ unsigned short lK[2][64 * 128];  // 2 x 16 KB
  alignas(16) __shared__ unsigned int lV[2][128 * 32];    // 2 x 16 KB

  const int tid = threadIdx.x;
  const int lane = tid & 63;
  const int w = tid >> 6;
  const int b = blockIdx.z;
  const int h = blockIdx.y;
  const int xa = blockIdx.x;  // 0..7
  const int kvh = h >> 2;

  const int fr = lane & 15;
  const int hi = lane >> 4;
  const int fk8 = hi << 3;
  const int hi4 = hi << 2;

  const int srow = tid >> 4;
  const int sc8 = (tid & 15) << 3;
  const int parity = srow & 1;
  const int vd0 = sc8 + (parity << 2);
  const int kscol = sc8 ^ ((srow & 7) << 3);

  const unsigned short* Kbp = QKV + (size_t)(b * 2048) * 6144 + 4096 + kvh * 128;
  const unsigned short* Vbp = Kbp + 1024;

  short8 vreg[4];
  unsigned int vw[4][4];

  // prologue: async-stage K(0) into lK[0]; load+pack V(0)
#pragma unroll
  for (int rep = 0; rep < 4; rep++)
    async16(&lK[0][rep * 2048 + tid * 8],
            Kbp + (size_t)(rep * 16 + srow) * 6144 + kscol);
#pragma unroll
  for (int rep = 0; rep < 4; rep++)
    vreg[rep] = *(const short8*)(Vbp + (size_t)(rep * 16 + srow) * 6144 + sc8);
  packV(vreg, parity, vw);

  for (int pass = 0; pass < 2; pass++) {
    const int x = pass ? (15 - xa) : xa;
    const int q0 = x * 128;
    const int nt = 2 * x + 2;

    short8 qf[2][4];
#pragma unroll
    for (int qsub = 0; qsub < 2; qsub++) {
      const unsigned short* qb =
          QKV + (size_t)(b * 2048 + q0 + w * 32 + qsub * 16 + fr) * 6144 + h * 128 + fk8;
#pragma unroll
      for (int ks = 0; ks < 4; ks++) qf[qsub][ks] = *(const short8*)(qb + ks * 32);
    }

    f32x4 oacc[2][8] = {};
    float m2[2] = {NEGBIG, NEGBIG};
    float ls[2] = {0.f, 0.f};

    for (int t = 0; t < nt; t++) {
      const int c = t & 1;
#pragma unroll
      for (int rep = 0; rep < 4; rep++) {
        int kvp = rep * 8 + (srow >> 1);
#pragma unroll
        for (int j = 0; j < 4; j++)
          lV[c][(vd0 + j) * 32 + (kvp ^ vswz(vd0 + j))] = vw[rep][j];
      }
      __syncthreads();  // drains vmcnt: K(t) asyncs + V loads complete

      if (t + 1 < nt) {
        const int kv1 = (t + 1) * 64;
#pragma unroll
        for (int rep = 0; rep < 4; rep++)
          async16(&lK[c ^ 1][rep * 2048 + tid * 8],
                  Kbp + (size_t)(kv1 + rep * 16 + srow) * 6144 + kscol);
#pragma unroll
        for (int rep = 0; rep < 4; rep++)
          vreg[rep] = *(const short8*)(Vbp + (size_t)(kv1 + rep * 16 + srow) * 6144 + sc8);
      } else if (pass == 0) {
#pragma unroll
        for (int rep = 0; rep < 4; rep++)
          async16(&lK[c ^ 1][rep * 2048 + tid * 8],
                  Kbp + (size_t)(rep * 16 + srow) * 6144 + kscol);
#pragma unroll
        for (int rep = 0; rep < 4; rep++)
          vreg[rep] = *(const short8*)(Vbp + (size_t)(rep * 16 + srow) * 6144 + sc8);
      }

      // S^T = mfma(K, Q): lane (fr,hi) holds S[q=fr][kv = fc*16 + hi*4 + r]
      f32x4 sacc[2][4] = {};
      __builtin_amdgcn_s_setprio(1);
#pragma unroll
      for (int fc = 0; fc < 4; fc++)
#pragma unroll
        for (int ks = 0; ks < 4; ks++) {
          short8 bk = *(const short8*)(&lK[c][(fc * 16 + fr) * 128 +
                                              ((ks * 32 + fk8) ^ ((fr & 7) << 3))]);
          sacc[0][fc] = __builtin_amdgcn_mfma_f32_16x16x32_bf16(bk, qf[0][ks], sacc[0][fc], 0, 0, 0);
          sacc[1][fc] = __builtin_amdgcn_mfma_f32_16x16x32_bf16(bk, qf[1][ks], sacc[1][fc], 0, 0, 0);
        }
      __builtin_amdgcn_s_setprio(0);

      const bool diag = (t >= nt - 2);
      const int kvb = t * 64;
      unsigned int pk[2][4][2];

#pragma unroll
      for (int qsub = 0; qsub < 2; qsub++) {
        const int q = q0 + w * 32 + qsub * 16 + fr;
        float sv[4][4];
#pragma unroll
        for (int fc = 0; fc < 4; fc++)
#pragma unroll
          for (int r = 0; r < 4; r++) {
            float xx = sacc[qsub][fc][r];
            if (diag && (kvb + fc * 16 + hi4 + r > q)) xx = NEGBIG;
            sv[fc][r] = xx;
          }
        float mx = sv[0][0];
#pragma unroll
        for (int fc = 0; fc < 4; fc++)
#pragma unroll
          for (int r = 0; r < 4; r++) mx = fmaxf(mx, sv[fc][r]);
        mx = fmaxf(mx, __shfl_xor(mx, 16));
        mx = fmaxf(mx, __shfl_xor(mx, 32));
        if (__any(mx > m2[qsub] + 8.0f)) {
          float mnew = fmaxf(m2[qsub], mx);
          float alpha = exp2_hw(m2[qsub] - mnew);
          m2[qsub] = mnew;
          ls[qsub] *= alpha;
          f32x4 av;
#pragma unroll
          for (int r = 0; r < 4; r++) av[r] = __shfl(alpha, hi4 + r);
#pragma unroll
          for (int nf = 0; nf < 8; nf++) oacc[qsub][nf] *= av;
        }
        float rs = 0.f;
        float p[4][4];
#pragma unroll
        for (int fc = 0; fc < 4; fc++)
#pragma unroll
          for (int r = 0; r < 4; r++) {
            p[fc][r] = exp2_hw(sv[fc][r] - m2[qsub]);
            rs += p[fc][r];
          }
        rs += __shfl_xor(rs, 16);
        rs += __shfl_xor(rs, 32);
        ls[qsub] += rs;
#pragma unroll
        for (int fc = 0; fc < 4; fc++) {
          pk[qsub][fc][0] = cvtpk_bf16(p[fc][0], p[fc][1]);
          pk[qsub][fc][1] = cvtpk_bf16(p[fc][2], p[fc][3]);
        }
      }

      // PV
      const int src0 = fr + ((hi & 1) << 5);
      const int src1 = src0 + 16;
#pragma unroll
      for (int kvs = 0; kvs < 2; kvs++) {
        unsigned int aw[2][4];
#pragma unroll
        for (int qsub = 0; qsub < 2; qsub++) {
#pragma unroll
          for (int jj = 0; jj < 4; jj++) {
            int src = (jj < 2) ? src0 : src1;
            int rr = jj & 1;
            unsigned int y0 = (unsigned)__shfl((int)pk[qsub][kvs * 2][rr], src);
            unsigned int y1 = (unsigned)__shfl((int)pk[qsub][kvs * 2 + 1][rr], src);
            aw[qsub][jj] = (hi >> 1) ? y1 : y0;
          }
        }
        int4v a0i = {(int)aw[0][0], (int)aw[0][1], (int)aw[0][2], (int)aw[0][3]};
        int4v a1i = {(int)aw[1][0], (int)aw[1][1], (int)aw[1][2], (int)aw[1][3]};
        short8 af0 = i4_to_s8(a0i), af1 = i4_to_s8(a1i);
        __builtin_amdgcn_s_setprio(1);
#pragma unroll
        for (int nf = 0; nf < 8; nf++) {
          int row = nf * 16 + fr;
          int4v bvw = *(const int4v*)(&lV[c][row * 32 + ((kvs * 16 + hi4) ^ vswz(row))]);
          short8 bv = i4_to_s8(bvw);
          oacc[0][nf] = __builtin_amdgcn_mfma_f32_16x16x32_bf16(af0, bv, oacc[0][nf], 0, 0, 0);
          oacc[1][nf] = __builtin_amdgcn_mfma_f32_16x16x32_bf16(af1, bv, oacc[1][nf], 0, 0, 0);
        }
        __builtin_amdgcn_s_setprio(0);
      }

      packV(vreg, parity, vw);
    }

    // epilogue for this pass
#pragma unroll
    for (int qsub = 0; qsub < 2; qsub++) {
      f32x4 iv;
#pragma unroll
      for (int r = 0; r < 4; r++) iv[r] = 1.0f / __shfl(ls[qsub], hi4 + r);
#pragma unroll
      for (int r = 0; r < 4; r++) {
        unsigned short* op =
            O + (size_t)(b * 2048 + q0 + w * 32 + qsub * 16 + hi4 + r) * 4096 + h * 128 + fr;
#pragma unroll
        for (int nf = 0; nf < 8; nf++) op[nf * 16] = f2bf(oacc[qsub][nf][r] * iv[r]);
      }
    }
  }
}

// ---------------------------------------------------------------------------
extern "C" void kernel_launch(void* const* d_in, const int* in_sizes, int n_in,
                              void* d_out, int out_size, void* d_ws, size_t ws_size,
                              hipStream_t stream) {
  const float* hs = (const float*)d_in[0];
  const float* wq = (const float*)d_in[1];
  const float* wk = (const float*)d_in[2];
  const float* wv = (const float*)d_in[3];
  const float* wo = (const float*)d_in[4];
  const float* cosb = (const float*)d_in[5];
  const float* sinb = (const float*)d_in[6];
  // d_in[7] attn_mask: pure causal, applied structurally

  unsigned short* ws = (unsigned short*)d_ws;
  unsigned short* T1 = ws;              // 4096x4096 (WqT, later WoT)
  unsigned short* T2 = T1 + 16777216;   // 1024x4096 (WkT)   } contiguous =
  unsigned short* T3 = T2 + 4194304;    // 1024x4096 (WvT)   } WqkvT 6144x4096
  unsigned short* QKV = T3 + 4194304;   // 4096x6144 (Q | K | V)
  unsigned short* Ob = QKV + 25165824;  // 4096x4096

  unsigned short* hsb = (unsigned short*)d_out;  // bf16 hs (consumed pre-O-gemm)

  downcast_f2b<<<8192, 256, 0, stream>>>(hs, hsb, 2097152);
  transpose64_f2b<<<dim3(64, 64), 256, 0, stream>>>(wq, T1, 4096, 4096);
  transpose64_f2b<<<dim3(16, 64), 256, 0, stream>>>(wk, T2, 4096, 1024);
  transpose64_f2b<<<dim3(16, 64), 256, 0, stream>>>(wv, T3, 4096, 1024);

  // merged QKV projection: C (4096 x 6144) = hs @ [Wq | Wk | Wv]
  // gemm2: 256x128 tiles -> 768 blocks = exactly 3/CU at 2 resident
  gemm2<<<dim3(16, 48), 512, 0, stream>>>(hsb, T1, QKV, 4096, 6144, 4096);

  // T1 free now: stage WoT
  transpose64_f2b<<<dim3(64, 64), 256, 0, stream>>>(wo, T1, 4096, 4096);

  // RoPE on Q (scaled by attscale*log2e -> exp2-domain softmax) and K
  const float qscale = 0.08838834764831845f * 1.4426950408889634f;
  rope_qk<<<5120, 256, 0, stream>>>(QKV, cosb, sinb, qscale);

  flash_attn<<<dim3(8, 32, 2), 256, 0, stream>>>(QKV, Ob);

  gemm8p<1><<<dim3(16, 16), 512, 0, stream>>>(Ob, T1, (float*)d_out, 4096, 4096, 4096);
}

// Round 21
// 528.483 us; speedup vs baseline: 1.0159x; 1.0159x over previous
//
#include <hip/hip_runtime.h>

typedef __attribute__((ext_vector_type(8))) short short8;
typedef __attribute__((ext_vector_type(4))) float f32x4;
typedef __attribute__((ext_vector_type(4))) int int4v;

__device__ __forceinline__ float bf2f(unsigned short u) {
  unsigned int x = ((unsigned int)u) << 16;
  float f;
  __builtin_memcpy(&f, &x, 4);
  return f;
}
__device__ __forceinline__ unsigned short f2bf(float f) {
  unsigned int x;
  __builtin_memcpy(&x, &f, 4);
  unsigned int r = (x + 0x7FFFu + ((x >> 16) & 1u)) >> 16;
  return (unsigned short)r;
}
__device__ __forceinline__ unsigned int cvtpk_bf16(float lo, float hi) {
  unsigned int r;
  asm("v_cvt_pk_bf16_f32 %0, %1, %2" : "=v"(r) : "v"(lo), "v"(hi));
  return r;
}
// hardware exp2: v_exp_f32 computes D = 2^S0
__device__ __forceinline__ float exp2_hw(float x) {
  float r;
  asm("v_exp_f32 %0, %1" : "=v"(r) : "v"(x));
  return r;
}
__device__ __forceinline__ int4v s8_to_i4(short8 v) {
  int4v r;
  __builtin_memcpy(&r, &v, 16);
  return r;
}
__device__ __forceinline__ short8 i4_to_s8(int4v v) {
  short8 r;
  __builtin_memcpy(&r, &v, 16);
  return r;
}
__device__ __forceinline__ short8 ld8_f32(const float* p) {
  f32x4 x = *(const f32x4*)p;
  f32x4 y = *(const f32x4*)(p + 4);
  short8 r;
  r[0] = (short)f2bf(x[0]); r[1] = (short)f2bf(x[1]);
  r[2] = (short)f2bf(x[2]); r[3] = (short)f2bf(x[3]);
  r[4] = (short)f2bf(y[0]); r[5] = (short)f2bf(y[1]);
  r[6] = (short)f2bf(y[2]); r[7] = (short)f2bf(y[3]);
  return r;
}

__device__ __forceinline__ void async16(unsigned short* lds, const unsigned short* g) {
  __builtin_amdgcn_global_load_lds(
      (const __attribute__((address_space(1))) void*)g,
      (__attribute__((address_space(3))) void*)lds, 16, 0, 0);
}

// ---------------------------------------------------------------------------
__global__ void downcast_f2b(const float* __restrict__ in,
                             unsigned short* __restrict__ out, int n8) {
  int i = blockIdx.x * 256 + threadIdx.x;
  if (i >= n8) return;
  *(short8*)(out + (size_t)i * 8) = ld8_f32(in + (size_t)i * 8);
}

// ---------------------------------------------------------------------------
// Vectorized transpose + downcast: in fp32 (R x C) -> out bf16 (C x R).
// ---------------------------------------------------------------------------
__global__ void transpose64_f2b(const float* __restrict__ in,
                                unsigned short* __restrict__ out, int R, int C) {
  alignas(16) __shared__ unsigned short t[64][72];
  const int c0 = blockIdx.x * 64;
  const int r0 = blockIdx.y * 64;
  const int tid = threadIdx.x;
  const int rr = tid >> 4;
  const int cc = (tid & 15) << 2;
#pragma unroll
  for (int i = 0; i < 4; i++) {
    int r = rr + i * 16;
    f32x4 v = *(const f32x4*)(in + (size_t)(r0 + r) * C + c0 + cc);
#pragma unroll
    for (int j = 0; j < 4; j++) t[cc + j][r] = f2bf(v[j]);
  }
  __syncthreads();
  const int seg = tid & 7;
  const int cr = tid >> 3;
#pragma unroll
  for (int i = 0; i < 2; i++) {
    int c = cr + i * 32;
    short8 w = *(const short8*)&t[c][seg * 8];
    *(short8*)(out + (size_t)(c0 + c) * R + r0 + seg * 8) = w;
  }
}

// ---------------------------------------------------------------------------
// GEMM 256x256, BK=64, 8 waves, 8-phase schedule (m201 template). Round-14
// form (validated: conflicts 0, ~1250 TF resident).
// ---------------------------------------------------------------------------
#define MFMA16(AF, B0, B1, N0, N1)                                                   \
  _Pragma("unroll") for (int mi = 0; mi < 8; mi++) {                                 \
    acc[mi][N0] = __builtin_amdgcn_mfma_f32_16x16x32_bf16(AF[mi], B0, acc[mi][N0], 0, 0, 0); \
    acc[mi][N1] = __builtin_amdgcn_mfma_f32_16x16x32_bf16(AF[mi], B1, acc[mi][N1], 0, 0, 0); \
  }

#define STAGE8(BUF, SLOT, BASE, KOFF)                                     \
  do {                                                                    \
    async16(&lds[BUF][SLOT][tid * 8], (BASE) + (KOFF));                   \
    async16(&lds[BUF][SLOT][4096 + tid * 8], (BASE) + Kstep128 + (KOFF)); \
  } while (0)

#define BAR8 asm volatile("s_barrier" ::: "memory")

#define TILE8(CUR, UU, S0, S123, VM)                                                   \
  do {                                                                                 \
    const int kb = (UU)*64;                                                            \
    short8 af[8], b0, b1;                                                              \
    /* ph0 (k0,L) */                                                                   \
    _Pragma("unroll") for (int mi = 0; mi < 8; mi++)                                   \
        af[mi] = *(const short8*)(&lds[CUR][0][(wr * 128 + mi * 16 + fr) * 32 + fragoff]); \
    b0 = *(const short8*)(&lds[CUR][2][(wc * 64 + 0 * 16 + fr) * 32 + fragoff]);       \
    b1 = *(const short8*)(&lds[CUR][2][(wc * 64 + 1 * 16 + fr) * 32 + fragoff]);       \
    if (S0) STAGE8((CUR) ^ 1, 3, Bbase, kb + 96);                                      \
    BAR8;                                                                              \
    __builtin_amdgcn_s_setprio(1);                                                     \
    MFMA16(af, b0, b1, 0, 1);                                                          \
    __builtin_amdgcn_s_setprio(0);                                                     \
    BAR8;                                                                              \
    /* ph1 (k0,R) */                                                                   \
    b0 = *(const short8*)(&lds[CUR][2][(wc * 64 + 2 * 16 + fr) * 32 + fragoff]);       \
    b1 = *(const short8*)(&lds[CUR][2][(wc * 64 + 3 * 16 + fr) * 32 + fragoff]);       \
    if (S123) STAGE8(CUR, 0, Abase, kb + 128);                                         \
    BAR8;                                                                              \
    __builtin_amdgcn_s_setprio(1);                                                     \
    MFMA16(af, b0, b1, 2, 3);                                                          \
    __builtin_amdgcn_s_setprio(0);                                                     \
    BAR8;                                                                              \
    /* ph2 (k1,L) */                                                                   \
    _Pragma("unroll") for (int mi = 0; mi < 8; mi++)                                   \
        af[mi] = *(const short8*)(&lds[CUR][1][(wr * 128 + mi * 16 + fr) * 32 + fragoff]); \
    b0 = *(const short8*)(&lds[CUR][3][(wc * 64 + 0 * 16 + fr) * 32 + fragoff]);       \
    b1 = *(const short8*)(&lds[CUR][3][(wc * 64 + 1 * 16 + fr) * 32 + fragoff]);       \
    if (S123) STAGE8(CUR, 2, Bbase, kb + 128);                                         \
    BAR8;                                                                              \
    __builtin_amdgcn_s_setprio(1);                                                     \
    MFMA16(af, b0, b1, 0, 1);                                                          \
    __builtin_amdgcn_s_setprio(0);                                                     \
    BAR8;                                                                              \
    /* ph3 (k1,R) */                                                                   \
    b0 = *(const short8*)(&lds[CUR][3][(wc * 64 + 2 * 16 + fr) * 32 + fragoff]);       \
    b1 = *(const short8*)(&lds[CUR][3][(wc * 64 + 3 * 16 + fr) * 32 + fragoff]);       \
    if (S123) STAGE8(CUR, 1, Abase, kb + 160);                                         \
    BAR8;                                                                              \
    __builtin_amdgcn_s_setprio(1);                                                     \
    MFMA16(af, b0, b1, 2, 3);                                                          \
    __builtin_amdgcn_s_setprio(0);                                                     \
    if ((VM) == 6) {                                                                   \
      asm volatile("s_waitcnt vmcnt(6)" ::: "memory");                                 \
      __builtin_amdgcn_sched_barrier(0);                                               \
    } else if ((VM) == 0) {                                                            \
      asm volatile("s_waitcnt vmcnt(0)" ::: "memory");                                 \
      __builtin_amdgcn_sched_barrier(0);                                               \
    }                                                                                  \
    BAR8;                                                                              \
  } while (0)

template <int CF32>
__global__ __launch_bounds__(512, 2) void gemm8p(
    const unsigned short* __restrict__ A, const unsigned short* __restrict__ BT,
    void* __restrict__ Cp, int M, int N, int K) {
  alignas(16) __shared__ unsigned short lds[2][4][8192];  // 128 KB
  const int tid = threadIdx.x;
  const int l = tid & 63;
  const int wv = tid >> 6;
  const int wr = wv >> 2, wc = wv & 3;

  const int nwg = gridDim.x * gridDim.y;
  int id = blockIdx.y * gridDim.x + blockIdx.x;
  id = (id & 7) * (nwg >> 3) + (id >> 3);
  const int bm = (id % gridDim.x) * 256;
  const int bn = (id / gridDim.x) * 256;

  const int fr = l & 15, hi = l >> 4;
  const int fragoff = ((hi ^ (((fr >> 3) & 1) << 1)) << 3);
  const int srow = tid >> 2;
  const int scol = (((tid & 3) ^ (((tid >> 5) & 1) << 1)) << 3);
  const unsigned short* Abase = A + (size_t)(bm + srow) * K + scol;
  const unsigned short* Bbase = BT + (size_t)(bn + srow) * K + scol;
  const size_t Kstep128 = (size_t)128 * K;

  f32x4 acc[8][4] = {};
  const int nt = K >> 6;

  STAGE8(0, 0, Abase, 0);
  STAGE8(0, 2, Bbase, 0);
  STAGE8(0, 1, Abase, 32);
  STAGE8(0, 3, Bbase, 32);
  STAGE8(1, 0, Abase, 64);
  STAGE8(1, 2, Bbase, 64);
  STAGE8(1, 1, Abase, 96);
  asm volatile("s_waitcnt vmcnt(6)" ::: "memory");
  __builtin_amdgcn_sched_barrier(0);
  BAR8;

  int U = 0;
  for (; U + 3 < nt; U += 2) {
    TILE8(0, U, 1, 1, 6);
    TILE8(1, U + 1, 1, 1, 6);
  }
  TILE8(0, nt - 2, 1, 0, 0);
  TILE8(1, nt - 1, 0, 0, -1);

  const int er = hi << 2;
#pragma unroll
  for (int mi = 0; mi < 8; mi++) {
#pragma unroll
    for (int ni = 0; ni < 4; ni++) {
      int row = bm + wr * 128 + mi * 16 + er;
      int col = bn + wc * 64 + ni * 16 + fr;
#pragma unroll
      for (int r = 0; r < 4; r++) {
        if constexpr (CF32)
          ((float*)Cp)[(size_t)(row + r) * N + col] = acc[mi][ni][r];
        else
          ((unsigned short*)Cp)[(size_t)(row + r) * N + col] = f2bf(acc[mi][ni][r]);
      }
    }
  }
}

// ---------------------------------------------------------------------------
// Merged RoPE on the QKV buffer (4096 tokens x 6144). Q region scaled by
// qscale (= attscale*log2e); K region unscaled.
// ---------------------------------------------------------------------------
__global__ void rope_qk(unsigned short* __restrict__ qkv,
                        const float* __restrict__ cosb,
                        const float* __restrict__ sinb, float qscale) {
  int gid = blockIdx.x * 256 + threadIdx.x;
  const int isK = gid >= 1048576;
  int g = isK ? gid - 1048576 : gid;
  const int nhs = isK ? 3 : 5;
  const int base = isK ? 4096 : 0;
  const float sc = isK ? 1.0f : qscale;
  int dblk = g & 7;
  int u2 = g >> 3;
  int head = u2 & ((1 << nhs) - 1);
  int token = u2 >> nhs;
  int s = token & 2047;
  int d0 = dblk << 3;
  unsigned short* p0 = qkv + (size_t)token * 6144 + base + (head << 7) + d0;
  unsigned short* p1 = p0 + 64;
  const float* cp = cosb + s * 128 + d0;
  const float* sp = sinb + s * 128 + d0;
  short8 a = *(const short8*)p0;
  short8 bq = *(const short8*)p1;
  f32x4 c0 = *(const f32x4*)cp, c1 = *(const f32x4*)(cp + 4);
  f32x4 s0 = *(const f32x4*)sp, s1 = *(const f32x4*)(sp + 4);
  short8 o0, o1;
#pragma unroll
  for (int j = 0; j < 8; j++) {
    float x0 = bf2f((unsigned short)a[j]);
    float x1 = bf2f((unsigned short)bq[j]);
    float c = (j < 4) ? c0[j & 3] : c1[j & 3];
    float sn = (j < 4) ? s0[j & 3] : s1[j & 3];
    o0[j] = (short)f2bf((x0 * c - x1 * sn) * sc);
    o1[j] = (short)f2bf((x1 * c + x0 * sn) * sc);
  }
  *(short8*)p0 = o0;
  *(short8*)p1 = o1;
}

// ---------------------------------------------------------------------------
// Flash attention: causal, GQA. QBLK=128 (4 waves x 32 q rows), KVBLK=64.
// Paired scheduling (uniform 34 kv-iters/block, grid 8x32x2), double-buffered
// lK/lV (one barrier per tile), K staged by global_load_lds direct into
// linear LDS with the XOR swizzle applied to the per-lane GLOBAL source
// column (rule #21 both-sides). V reg-staged + shfl-packed at the end of
// the compute phase. Q pre-scaled by attscale*log2e; exp2-domain softmax;
// defer-max rescale. launch_bounds (256,2): ~128 VGPR, no spill.
// ---------------------------------------------------------------------------
#define NEGBIG -30000.0f

__device__ __forceinline__ int vswz(int d) { return (((d >> 3) ^ d) & 7) << 2; }

__device__ __forceinline__ void packV(const short8 vreg[4], int parity,
                                      unsigned int vw[4][4]) {
#pragma unroll
  for (int rep = 0; rep < 4; rep++) {
    int4v own = s8_to_i4(vreg[rep]);
    int4v oth;
#pragma unroll
    for (int q = 0; q < 4; q++) oth[q] = __shfl_xor(own[q], 16);
    unsigned int oA = parity ? (unsigned)own[2] : (unsigned)own[0];
    unsigned int oB = parity ? (unsigned)own[3] : (unsigned)own[1];
    unsigned int tA = parity ? (unsigned)oth[2] : (unsigned)oth[0];
    unsigned int tB = parity ? (unsigned)oth[3] : (unsigned)oth[1];
    unsigned int evA = parity ? tA : oA, odA = parity ? oA : tA;
    unsigned int evB = parity ? tB : oB, odB = parity ? oB : tB;
    vw[rep][0] = (evA & 0xFFFFu) | (odA << 16);
    vw[rep][1] = (evA >> 16) | (odA & 0xFFFF0000u);
    vw[rep][2] = (evB & 0xFFFFu) | (odB << 16);
    vw[rep][3] = (evB >> 16) | (odB & 0xFFFF0000u);
  }
}

__global__ __launch_bounds__(256, 2) void flash_attn(
    const unsigned short* __restrict__ QKV, unsigned short* __restrict__ O) {
  alignas(16) __shared__ unsigned short lK[2][64 * 128];  // 2 x 16 KB
  alignas(16) __shared__ unsigned int lV[2][128 * 32];    // 2 x 16 KB

  const int tid = threadIdx.x;
  const int lane = tid & 63;
  const int w = tid >> 6;
  const int b = blockIdx.z;
  const int h = blockIdx.y;
  const int xa = blockIdx.x;  // 0..7
  const int kvh = h >> 2;

  const int fr = lane & 15;
  const int hi = lane >> 4;
  const int fk8 = hi << 3;
  const int hi4 = hi << 2;

  const int srow = tid >> 4;
  const int sc8 = (tid & 15) << 3;
  const int parity = srow & 1;
  const int vd0 = sc8 + (parity << 2);
  const int kscol = sc8 ^ ((srow & 7) << 3);

  const unsigned short* Kbp = QKV + (size_t)(b * 2048) * 6144 + 4096 + kvh * 128;
  const unsigned short* Vbp = Kbp + 1024;

  short8 vreg[4];
  unsigned int vw[4][4];

  // prologue: async-stage K(0) into lK[0]; load+pack V(0)
#pragma unroll
  for (int rep = 0; rep < 4; rep++)
    async16(&lK[0][rep * 2048 + tid * 8],
            Kbp + (size_t)(rep * 16 + srow) * 6144 + kscol);
#pragma unroll
  for (int rep = 0; rep < 4; rep++)
    vreg[rep] = *(const short8*)(Vbp + (size_t)(rep * 16 + srow) * 6144 + sc8);
  packV(vreg, parity, vw);

  for (int pass = 0; pass < 2; pass++) {
    const int x = pass ? (15 - xa) : xa;
    const int q0 = x * 128;
    const int nt = 2 * x + 2;

    short8 qf[2][4];
#pragma unroll
    for (int qsub = 0; qsub < 2; qsub++) {
      const unsigned short* qb =
          QKV + (size_t)(b * 2048 + q0 + w * 32 + qsub * 16 + fr) * 6144 + h * 128 + fk8;
#pragma unroll
      for (int ks = 0; ks < 4; ks++) qf[qsub][ks] = *(const short8*)(qb + ks * 32);
    }

    f32x4 oacc[2][8] = {};
    float m2[2] = {NEGBIG, NEGBIG};
    float ls[2] = {0.f, 0.f};

    for (int t = 0; t < nt; t++) {
      const int c = t & 1;
#pragma unroll
      for (int rep = 0; rep < 4; rep++) {
        int kvp = rep * 8 + (srow >> 1);
#pragma unroll
        for (int j = 0; j < 4; j++)
          lV[c][(vd0 + j) * 32 + (kvp ^ vswz(vd0 + j))] = vw[rep][j];
      }
      __syncthreads();  // drains vmcnt: K(t) asyncs + V loads complete

      if (t + 1 < nt) {
        const int kv1 = (t + 1) * 64;
#pragma unroll
        for (int rep = 0; rep < 4; rep++)
          async16(&lK[c ^ 1][rep * 2048 + tid * 8],
                  Kbp + (size_t)(kv1 + rep * 16 + srow) * 6144 + kscol);
#pragma unroll
        for (int rep = 0; rep < 4; rep++)
          vreg[rep] = *(const short8*)(Vbp + (size_t)(kv1 + rep * 16 + srow) * 6144 + sc8);
      } else if (pass == 0) {
#pragma unroll
        for (int rep = 0; rep < 4; rep++)
          async16(&lK[c ^ 1][rep * 2048 + tid * 8],
                  Kbp + (size_t)(rep * 16 + srow) * 6144 + kscol);
#pragma unroll
        for (int rep = 0; rep < 4; rep++)
          vreg[rep] = *(const short8*)(Vbp + (size_t)(rep * 16 + srow) * 6144 + sc8);
      }

      // S^T = mfma(K, Q): lane (fr,hi) holds S[q=fr][kv = fc*16 + hi*4 + r]
      f32x4 sacc[2][4] = {};
      __builtin_amdgcn_s_setprio(1);
#pragma unroll
      for (int fc = 0; fc < 4; fc++)
#pragma unroll
        for (int ks = 0; ks < 4; ks++) {
          short8 bk = *(const short8*)(&lK[c][(fc * 16 + fr) * 128 +
                                              ((ks * 32 + fk8) ^ ((fr & 7) << 3))]);
          sacc[0][fc] = __builtin_amdgcn_mfma_f32_16x16x32_bf16(bk, qf[0][ks], sacc[0][fc], 0, 0, 0);
          sacc[1][fc] = __builtin_amdgcn_mfma_f32_16x16x32_bf16(bk, qf[1][ks], sacc[1][fc], 0, 0, 0);
        }
      __builtin_amdgcn_s_setprio(0);

      const bool diag = (t >= nt - 2);
      const int kvb = t * 64;
      unsigned int pk[2][4][2];

#pragma unroll
      for (int qsub = 0; qsub < 2; qsub++) {
        const int q = q0 + w * 32 + qsub * 16 + fr;
        float sv[4][4];
#pragma unroll
        for (int fc = 0; fc < 4; fc++)
#pragma unroll
          for (int r = 0; r < 4; r++) {
            float xx = sacc[qsub][fc][r];
            if (diag && (kvb + fc * 16 + hi4 + r > q)) xx = NEGBIG;
            sv[fc][r] = xx;
          }
        float mx = sv[0][0];
#pragma unroll
        for (int fc = 0; fc < 4; fc++)
#pragma unroll
          for (int r = 0; r < 4; r++) mx = fmaxf(mx, sv[fc][r]);
        mx = fmaxf(mx, __shfl_xor(mx, 16));
        mx = fmaxf(mx, __shfl_xor(mx, 32));
        if (__any(mx > m2[qsub] + 8.0f)) {
          float mnew = fmaxf(m2[qsub], mx);
          float alpha = exp2_hw(m2[qsub] - mnew);
          m2[qsub] = mnew;
          ls[qsub] *= alpha;
          f32x4 av;
#pragma unroll
          for (int r = 0; r < 4; r++) av[r] = __shfl(alpha, hi4 + r);
#pragma unroll
          for (int nf = 0; nf < 8; nf++) oacc[qsub][nf] *= av;
        }
        float rs = 0.f;
        float p[4][4];
#pragma unroll
        for (int fc = 0; fc < 4; fc++)
#pragma unroll
          for (int r = 0; r < 4; r++) {
            p[fc][r] = exp2_hw(sv[fc][r] - m2[qsub]);
            rs += p[fc][r];
          }
        rs += __shfl_xor(rs, 16);
        rs += __shfl_xor(rs, 32);
        ls[qsub] += rs;
#pragma unroll
        for (int fc = 0; fc < 4; fc++) {
          pk[qsub][fc][0] = cvtpk_bf16(p[fc][0], p[fc][1]);
          pk[qsub][fc][1] = cvtpk_bf16(p[fc][2], p[fc][3]);
        }
      }

      // PV
      const int src0 = fr + ((hi & 1) << 5);
      const int src1 = src0 + 16;
#pragma unroll
      for (int kvs = 0; kvs < 2; kvs++) {
        unsigned int aw[2][4];
#pragma unroll
        for (int qsub = 0; qsub < 2; qsub++) {
#pragma unroll
          for (int jj = 0; jj < 4; jj++) {
            int src = (jj < 2) ? src0 : src1;
            int rr = jj & 1;
            unsigned int y0 = (unsigned)__shfl((int)pk[qsub][kvs * 2][rr], src);
            unsigned int y1 = (unsigned)__shfl((int)pk[qsub][kvs * 2 + 1][rr], src);
            aw[qsub][jj] = (hi >> 1) ? y1 : y0;
          }
        }
        int4v a0i = {(int)aw[0][0], (int)aw[0][1], (int)aw[0][2], (int)aw[0][3]};
        int4v a1i = {(int)aw[1][0], (int)aw[1][1], (int)aw[1][2], (int)aw[1][3]};
        short8 af0 = i4_to_s8(a0i), af1 = i4_to_s8(a1i);
        __builtin_amdgcn_s_setprio(1);
#pragma unroll
        for (int nf = 0; nf < 8; nf++) {
          int row = nf * 16 + fr;
          int4v bvw = *(const int4v*)(&lV[c][row * 32 + ((kvs * 16 + hi4) ^ vswz(row))]);
          short8 bv = i4_to_s8(bvw);
          oacc[0][nf] = __builtin_amdgcn_mfma_f32_16x16x32_bf16(af0, bv, oacc[0][nf], 0, 0, 0);
          oacc[1][nf] = __builtin_amdgcn_mfma_f32_16x16x32_bf16(af1, bv, oacc[1][nf], 0, 0, 0);
        }
        __builtin_amdgcn_s_setprio(0);
      }

      packV(vreg, parity, vw);
    }

    // epilogue for this pass
#pragma unroll
    for (int qsub = 0; qsub < 2; qsub++) {
      f32x4 iv;
#pragma unroll
      for (int r = 0; r < 4; r++) iv[r] = 1.0f / __shfl(ls[qsub], hi4 + r);
#pragma unroll
      for (int r = 0; r < 4; r++) {
        unsigned short* op =
            O + (size_t)(b * 2048 + q0 + w * 32 + qsub * 16 + hi4 + r) * 4096 + h * 128 + fr;
#pragma unroll
        for (int nf = 0; nf < 8; nf++) op[nf * 16] = f2bf(oacc[qsub][nf][r] * iv[r]);
      }
    }
  }
}

// ---------------------------------------------------------------------------
extern "C" void kernel_launch(void* const* d_in, const int* in_sizes, int n_in,
                              void* d_out, int out_size, void* d_ws, size_t ws_size,
                              hipStream_t stream) {
  const float* hs = (const float*)d_in[0];
  const float* wq = (const float*)d_in[1];
  const float* wk = (const float*)d_in[2];
  const float* wv = (const float*)d_in[3];
  const float* wo = (const float*)d_in[4];
  const float* cosb = (const float*)d_in[5];
  const float* sinb = (const float*)d_in[6];
  // d_in[7] attn_mask: pure causal, applied structurally

  unsigned short* ws = (unsigned short*)d_ws;
  unsigned short* T1 = ws;              // 4096x4096 (WqT, later WoT)
  unsigned short* T2 = T1 + 16777216;   // 1024x4096 (WkT)   } contiguous =
  unsigned short* T3 = T2 + 4194304;    // 1024x4096 (WvT)   } WqkvT 6144x4096
  unsigned short* QKV = T3 + 4194304;   // 4096x6144 (Q | K | V)
  unsigned short* Ob = QKV + 25165824;  // 4096x4096

  unsigned short* hsb = (unsigned short*)d_out;  // bf16 hs (consumed pre-O-gemm)

  downcast_f2b<<<8192, 256, 0, stream>>>(hs, hsb, 2097152);
  transpose64_f2b<<<dim3(64, 64), 256, 0, stream>>>(wq, T1, 4096, 4096);
  transpose64_f2b<<<dim3(16, 64), 256, 0, stream>>>(wk, T2, 4096, 1024);
  transpose64_f2b<<<dim3(16, 64), 256, 0, stream>>>(wv, T3, 4096, 1024);

  // merged QKV projection: C (4096 x 6144) = hs @ [Wq | Wk | Wv]
  gemm8p<0><<<dim3(16, 24), 512, 0, stream>>>(hsb, T1, QKV, 4096, 6144, 4096);

  // T1 free now: stage WoT
  transpose64_f2b<<<dim3(64, 64), 256, 0, stream>>>(wo, T1, 4096, 4096);

  // RoPE on Q (scaled by attscale*log2e -> exp2-domain softmax) and K
  const float qscale = 0.08838834764831845f * 1.4426950408889634f;
  rope_qk<<<5120, 256, 0, stream>>>(QKV, cosb, sinb, qscale);

  flash_attn<<<dim3(8, 32, 2), 256, 0, stream>>>(QKV, Ob);

  gemm8p<1><<<dim3(16, 16), 512, 0, stream>>>(Ob, T1, (float*)d_out, 4096, 4096, 4096);
}

// Round 22
// 527.573 us; speedup vs baseline: 1.0177x; 1.0017x over previous
//
#include <hip/hip_runtime.h>

typedef __attribute__((ext_vector_type(8))) short short8;
typedef __attribute__((ext_vector_type(4))) float f32x4;
typedef __attribute__((ext_vector_type(4))) int int4v;

__device__ __forceinline__ float bf2f(unsigned short u) {
  unsigned int x = ((unsigned int)u) << 16;
  float f;
  __builtin_memcpy(&f, &x, 4);
  return f;
}
__device__ __forceinline__ unsigned short f2bf(float f) {
  unsigned int x;
  __builtin_memcpy(&x, &f, 4);
  unsigned int r = (x + 0x7FFFu + ((x >> 16) & 1u)) >> 16;
  return (unsigned short)r;
}
__device__ __forceinline__ unsigned int cvtpk_bf16(float lo, float hi) {
  unsigned int r;
  asm("v_cvt_pk_bf16_f32 %0, %1, %2" : "=v"(r) : "v"(lo), "v"(hi));
  return r;
}
// hardware exp2: v_exp_f32 computes D = 2^S0
__device__ __forceinline__ float exp2_hw(float x) {
  float r;
  asm("v_exp_f32 %0, %1" : "=v"(r) : "v"(x));
  return r;
}
__device__ __forceinline__ int4v s8_to_i4(short8 v) {
  int4v r;
  __builtin_memcpy(&r, &v, 16);
  return r;
}
__device__ __forceinline__ short8 i4_to_s8(int4v v) {
  short8 r;
  __builtin_memcpy(&r, &v, 16);
  return r;
}
__device__ __forceinline__ short8 ld8_f32(const float* p) {
  f32x4 x = *(const f32x4*)p;
  f32x4 y = *(const f32x4*)(p + 4);
  short8 r;
  r[0] = (short)f2bf(x[0]); r[1] = (short)f2bf(x[1]);
  r[2] = (short)f2bf(x[2]); r[3] = (short)f2bf(x[3]);
  r[4] = (short)f2bf(y[0]); r[5] = (short)f2bf(y[1]);
  r[6] = (short)f2bf(y[2]); r[7] = (short)f2bf(y[3]);
  return r;
}

__device__ __forceinline__ void async16(unsigned short* lds, const unsigned short* g) {
  __builtin_amdgcn_global_load_lds(
      (const __attribute__((address_space(1))) void*)g,
      (__attribute__((address_space(3))) void*)lds, 16, 0, 0);
}

// ---------------------------------------------------------------------------
__global__ void downcast_f2b(const float* __restrict__ in,
                             unsigned short* __restrict__ out, int n8) {
  int i = blockIdx.x * 256 + threadIdx.x;
  if (i >= n8) return;
  *(short8*)(out + (size_t)i * 8) = ld8_f32(in + (size_t)i * 8);
}

// ---------------------------------------------------------------------------
// Vectorized transpose + downcast: in fp32 (R x C) -> out bf16 (C x R).
// ---------------------------------------------------------------------------
__global__ void transpose64_f2b(const float* __restrict__ in,
                                unsigned short* __restrict__ out, int R, int C) {
  alignas(16) __shared__ unsigned short t[64][72];
  const int c0 = blockIdx.x * 64;
  const int r0 = blockIdx.y * 64;
  const int tid = threadIdx.x;
  const int rr = tid >> 4;
  const int cc = (tid & 15) << 2;
#pragma unroll
  for (int i = 0; i < 4; i++) {
    int r = rr + i * 16;
    f32x4 v = *(const f32x4*)(in + (size_t)(r0 + r) * C + c0 + cc);
#pragma unroll
    for (int j = 0; j < 4; j++) t[cc + j][r] = f2bf(v[j]);
  }
  __syncthreads();
  const int seg = tid & 7;
  const int cr = tid >> 3;
#pragma unroll
  for (int i = 0; i < 2; i++) {
    int c = cr + i * 32;
    short8 w = *(const short8*)&t[c][seg * 8];
    *(short8*)(out + (size_t)(c0 + c) * R + r0 + seg * 8) = w;
  }
}

// ---------------------------------------------------------------------------
// GEMM 256x256, BK=64, 8 waves, 8-phase schedule (m201 template). Round-14
// form (validated: conflicts 0, ~1250 TF resident).
// ---------------------------------------------------------------------------
#define MFMA16(AF, B0, B1, N0, N1)                                                   \
  _Pragma("unroll") for (int mi = 0; mi < 8; mi++) {                                 \
    acc[mi][N0] = __builtin_amdgcn_mfma_f32_16x16x32_bf16(AF[mi], B0, acc[mi][N0], 0, 0, 0); \
    acc[mi][N1] = __builtin_amdgcn_mfma_f32_16x16x32_bf16(AF[mi], B1, acc[mi][N1], 0, 0, 0); \
  }

#define STAGE8(BUF, SLOT, BASE, KOFF)                                     \
  do {                                                                    \
    async16(&lds[BUF][SLOT][tid * 8], (BASE) + (KOFF));                   \
    async16(&lds[BUF][SLOT][4096 + tid * 8], (BASE) + Kstep128 + (KOFF)); \
  } while (0)

#define BAR8 asm volatile("s_barrier" ::: "memory")

#define TILE8(CUR, UU, S0, S123, VM)                                                   \
  do {                                                                                 \
    const int kb = (UU)*64;                                                            \
    short8 af[8], b0, b1;                                                              \
    /* ph0 (k0,L) */                                                                   \
    _Pragma("unroll") for (int mi = 0; mi < 8; mi++)                                   \
        af[mi] = *(const short8*)(&lds[CUR][0][(wr * 128 + mi * 16 + fr) * 32 + fragoff]); \
    b0 = *(const short8*)(&lds[CUR][2][(wc * 64 + 0 * 16 + fr) * 32 + fragoff]);       \
    b1 = *(const short8*)(&lds[CUR][2][(wc * 64 + 1 * 16 + fr) * 32 + fragoff]);       \
    if (S0) STAGE8((CUR) ^ 1, 3, Bbase, kb + 96);                                      \
    BAR8;                                                                              \
    __builtin_amdgcn_s_setprio(1);                                                     \
    MFMA16(af, b0, b1, 0, 1);                                                          \
    __builtin_amdgcn_s_setprio(0);                                                     \
    BAR8;                                                                              \
    /* ph1 (k0,R) */                                                                   \
    b0 = *(const short8*)(&lds[CUR][2][(wc * 64 + 2 * 16 + fr) * 32 + fragoff]);       \
    b1 = *(const short8*)(&lds[CUR][2][(wc * 64 + 3 * 16 + fr) * 32 + fragoff]);       \
    if (S123) STAGE8(CUR, 0, Abase, kb + 128);                                         \
    BAR8;                                                                              \
    __builtin_amdgcn_s_setprio(1);                                                     \
    MFMA16(af, b0, b1, 2, 3);                                                          \
    __builtin_amdgcn_s_setprio(0);                                                     \
    BAR8;                                                                              \
    /* ph2 (k1,L) */                                                                   \
    _Pragma("unroll") for (int mi = 0; mi < 8; mi++)                                   \
        af[mi] = *(const short8*)(&lds[CUR][1][(wr * 128 + mi * 16 + fr) * 32 + fragoff]); \
    b0 = *(const short8*)(&lds[CUR][3][(wc * 64 + 0 * 16 + fr) * 32 + fragoff]);       \
    b1 = *(const short8*)(&lds[CUR][3][(wc * 64 + 1 * 16 + fr) * 32 + fragoff]);       \
    if (S123) STAGE8(CUR, 2, Bbase, kb + 128);                                         \
    BAR8;                                                                              \
    __builtin_amdgcn_s_setprio(1);                                                     \
    MFMA16(af, b0, b1, 0, 1);                                                          \
    __builtin_amdgcn_s_setprio(0);                                                     \
    BAR8;                                                                              \
    /* ph3 (k1,R) */                                                                   \
    b0 = *(const short8*)(&lds[CUR][3][(wc * 64 + 2 * 16 + fr) * 32 + fragoff]);       \
    b1 = *(const short8*)(&lds[CUR][3][(wc * 64 + 3 * 16 + fr) * 32 + fragoff]);       \
    if (S123) STAGE8(CUR, 1, Abase, kb + 160);                                         \
    BAR8;                                                                              \
    __builtin_amdgcn_s_setprio(1);                                                     \
    MFMA16(af, b0, b1, 2, 3);                                                          \
    __builtin_amdgcn_s_setprio(0);                                                     \
    if ((VM) == 6) {                                                                   \
      asm volatile("s_waitcnt vmcnt(6)" ::: "memory");                                 \
      __builtin_amdgcn_sched_barrier(0);                                               \
    } else if ((VM) == 0) {                                                            \
      asm volatile("s_waitcnt vmcnt(0)" ::: "memory");                                 \
      __builtin_amdgcn_sched_barrier(0);                                               \
    }                                                                                  \
    BAR8;                                                                              \
  } while (0)

template <int CF32>
__global__ __launch_bounds__(512, 2) void gemm8p(
    const unsigned short* __restrict__ A, const unsigned short* __restrict__ BT,
    void* __restrict__ Cp, int M, int N, int K) {
  alignas(16) __shared__ unsigned short lds[2][4][8192];  // 128 KB
  const int tid = threadIdx.x;
  const int l = tid & 63;
  const int wv = tid >> 6;
  const int wr = wv >> 2, wc = wv & 3;

  const int nwg = gridDim.x * gridDim.y;
  int id = blockIdx.y * gridDim.x + blockIdx.x;
  id = (id & 7) * (nwg >> 3) + (id >> 3);
  const int bm = (id % gridDim.x) * 256;
  const int bn = (id / gridDim.x) * 256;

  const int fr = l & 15, hi = l >> 4;
  const int fragoff = ((hi ^ (((fr >> 3) & 1) << 1)) << 3);
  const int srow = tid >> 2;
  const int scol = (((tid & 3) ^ (((tid >> 5) & 1) << 1)) << 3);
  const unsigned short* Abase = A + (size_t)(bm + srow) * K + scol;
  const unsigned short* Bbase = BT + (size_t)(bn + srow) * K + scol;
  const size_t Kstep128 = (size_t)128 * K;

  f32x4 acc[8][4] = {};
  const int nt = K >> 6;

  STAGE8(0, 0, Abase, 0);
  STAGE8(0, 2, Bbase, 0);
  STAGE8(0, 1, Abase, 32);
  STAGE8(0, 3, Bbase, 32);
  STAGE8(1, 0, Abase, 64);
  STAGE8(1, 2, Bbase, 64);
  STAGE8(1, 1, Abase, 96);
  asm volatile("s_waitcnt vmcnt(6)" ::: "memory");
  __builtin_amdgcn_sched_barrier(0);
  BAR8;

  int U = 0;
  for (; U + 3 < nt; U += 2) {
    TILE8(0, U, 1, 1, 6);
    TILE8(1, U + 1, 1, 1, 6);
  }
  TILE8(0, nt - 2, 1, 0, 0);
  TILE8(1, nt - 1, 0, 0, -1);

  const int er = hi << 2;
#pragma unroll
  for (int mi = 0; mi < 8; mi++) {
#pragma unroll
    for (int ni = 0; ni < 4; ni++) {
      int row = bm + wr * 128 + mi * 16 + er;
      int col = bn + wc * 64 + ni * 16 + fr;
#pragma unroll
      for (int r = 0; r < 4; r++) {
        if constexpr (CF32)
          ((float*)Cp)[(size_t)(row + r) * N + col] = acc[mi][ni][r];
        else
          ((unsigned short*)Cp)[(size_t)(row + r) * N + col] = f2bf(acc[mi][ni][r]);
      }
    }
  }
}

// ---------------------------------------------------------------------------
// RoPE on the K region only (cols 4096..5119 of the QKV buffer); Q-RoPE is
// fused into flash_attn's Q fragment load. 262144 threads = 1024 blocks.
// ---------------------------------------------------------------------------
__global__ void rope_k(unsigned short* __restrict__ qkv,
                       const float* __restrict__ cosb,
                       const float* __restrict__ sinb) {
  int gid = blockIdx.x * 256 + threadIdx.x;
  int dblk = gid & 7;
  int u2 = gid >> 3;
  int head = u2 & 7;
  int token = u2 >> 3;
  int s = token & 2047;
  int d0 = dblk << 3;
  unsigned short* p0 = qkv + (size_t)token * 6144 + 4096 + (head << 7) + d0;
  unsigned short* p1 = p0 + 64;
  const float* cp = cosb + s * 128 + d0;
  const float* sp = sinb + s * 128 + d0;
  short8 a = *(const short8*)p0;
  short8 bq = *(const short8*)p1;
  f32x4 c0 = *(const f32x4*)cp, c1 = *(const f32x4*)(cp + 4);
  f32x4 s0 = *(const f32x4*)sp, s1 = *(const f32x4*)(sp + 4);
  short8 o0, o1;
#pragma unroll
  for (int j = 0; j < 8; j++) {
    float x0 = bf2f((unsigned short)a[j]);
    float x1 = bf2f((unsigned short)bq[j]);
    float c = (j < 4) ? c0[j & 3] : c1[j & 3];
    float sn = (j < 4) ? s0[j & 3] : s1[j & 3];
    o0[j] = (short)f2bf(x0 * c - x1 * sn);
    o1[j] = (short)f2bf(x1 * c + x0 * sn);
  }
  *(short8*)p0 = o0;
  *(short8*)p1 = o1;
}

// ---------------------------------------------------------------------------
// Flash attention: causal, GQA. QBLK=128 (4 waves x 32 q rows), KVBLK=64.
// Paired scheduling (uniform 34 kv-iters/block, grid 8x32x2), double-buffered
// lK/lV (one barrier per tile), K staged by global_load_lds direct (swizzled
// global source), V reg-staged + shfl-packed.
// Round-22: Q-RoPE (+ attscale*log2e) fused into the Q fragment load — each
// thread holds both rotate-half partners (qf[ks] col d, qf[ks+2] col d+64),
// and cos[s][d]==cos[s][d+64], so the rotation is thread-local. Bit-identical
// to the previous rope-kernel path (same bf16->f32->rotate->bf16 chain).
// exp2-domain softmax; defer-max rescale. launch_bounds (256,2): no spill.
// ---------------------------------------------------------------------------
#define NEGBIG -30000.0f

__device__ __forceinline__ int vswz(int d) { return (((d >> 3) ^ d) & 7) << 2; }

__device__ __forceinline__ void packV(const short8 vreg[4], int parity,
                                      unsigned int vw[4][4]) {
#pragma unroll
  for (int rep = 0; rep < 4; rep++) {
    int4v own = s8_to_i4(vreg[rep]);
    int4v oth;
#pragma unroll
    for (int q = 0; q < 4; q++) oth[q] = __shfl_xor(own[q], 16);
    unsigned int oA = parity ? (unsigned)own[2] : (unsigned)own[0];
    unsigned int oB = parity ? (unsigned)own[3] : (unsigned)own[1];
    unsigned int tA = parity ? (unsigned)oth[2] : (unsigned)oth[0];
    unsigned int tB = parity ? (unsigned)oth[3] : (unsigned)oth[1];
    unsigned int evA = parity ? tA : oA, odA = parity ? oA : tA;
    unsigned int evB = parity ? tB : oB, odB = parity ? oB : tB;
    vw[rep][0] = (evA & 0xFFFFu) | (odA << 16);
    vw[rep][1] = (evA >> 16) | (odA & 0xFFFF0000u);
    vw[rep][2] = (evB & 0xFFFFu) | (odB << 16);
    vw[rep][3] = (evB >> 16) | (odB & 0xFFFF0000u);
  }
}

__global__ __launch_bounds__(256, 2) void flash_attn(
    const unsigned short* __restrict__ QKV, unsigned short* __restrict__ O,
    const float* __restrict__ cosb, const float* __restrict__ sinb,
    float qscale) {
  alignas(16) __shared__ unsigned short lK[2][64 * 128];  // 2 x 16 KB
  alignas(16) __shared__ unsigned int lV[2][128 * 32];    // 2 x 16 KB

  const int tid = threadIdx.x;
  const int lane = tid & 63;
  const int w = tid >> 6;
  const int b = blockIdx.z;
  const int h = blockIdx.y;
  const int xa = blockIdx.x;  // 0..7
  const int kvh = h >> 2;

  const int fr = lane & 15;
  const int hi = lane >> 4;
  const int fk8 = hi << 3;
  const int hi4 = hi << 2;

  const int srow = tid >> 4;
  const int sc8 = (tid & 15) << 3;
  const int parity = srow & 1;
  const int vd0 = sc8 + (parity << 2);
  const int kscol = sc8 ^ ((srow & 7) << 3);

  const unsigned short* Kbp = QKV + (size_t)(b * 2048) * 6144 + 4096 + kvh * 128;
  const unsigned short* Vbp = Kbp + 1024;

  short8 vreg[4];
  unsigned int vw[4][4];

  // prologue: async-stage K(0) into lK[0]; load+pack V(0)
#pragma unroll
  for (int rep = 0; rep < 4; rep++)
    async16(&lK[0][rep * 2048 + tid * 8],
            Kbp + (size_t)(rep * 16 + srow) * 6144 + kscol);
#pragma unroll
  for (int rep = 0; rep < 4; rep++)
    vreg[rep] = *(const short8*)(Vbp + (size_t)(rep * 16 + srow) * 6144 + sc8);
  packV(vreg, parity, vw);

  for (int pass = 0; pass < 2; pass++) {
    const int x = pass ? (15 - xa) : xa;
    const int q0 = x * 128;
    const int nt = 2 * x + 2;

    // Q fragments with fused RoPE + qscale. Thread-local rotate-half:
    // raw[ks] holds col d = ks*32+fk8+j (d<64 for ks<2), raw[ks+2] holds d+64.
    short8 qf[2][4];
#pragma unroll
    for (int qsub = 0; qsub < 2; qsub++) {
      const int s = q0 + w * 32 + qsub * 16 + fr;  // token position (0..2047)
      const unsigned short* qb =
          QKV + (size_t)(b * 2048 + s) * 6144 + h * 128 + fk8;
      short8 raw[4];
#pragma unroll
      for (int ks = 0; ks < 4; ks++) raw[ks] = *(const short8*)(qb + ks * 32);
#pragma unroll
      for (int ks = 0; ks < 2; ks++) {
        const float* cp = cosb + s * 128 + ks * 32 + fk8;
        const float* sp = sinb + s * 128 + ks * 32 + fk8;
        f32x4 c0 = *(const f32x4*)cp, c1 = *(const f32x4*)(cp + 4);
        f32x4 s0 = *(const f32x4*)sp, s1 = *(const f32x4*)(sp + 4);
        short8 o0, o1;
#pragma unroll
        for (int j = 0; j < 8; j++) {
          float x0 = bf2f((unsigned short)raw[ks][j]);
          float x1 = bf2f((unsigned short)raw[ks + 2][j]);
          float c = (j < 4) ? c0[j & 3] : c1[j & 3];
          float sn = (j < 4) ? s0[j & 3] : s1[j & 3];
          o0[j] = (short)f2bf((x0 * c - x1 * sn) * qscale);
          o1[j] = (short)f2bf((x1 * c + x0 * sn) * qscale);
        }
        qf[qsub][ks] = o0;
        qf[qsub][ks + 2] = o1;
      }
    }

    f32x4 oacc[2][8] = {};
    float m2[2] = {NEGBIG, NEGBIG};
    float ls[2] = {0.f, 0.f};

    for (int t = 0; t < nt; t++) {
      const int c = t & 1;
#pragma unroll
      for (int rep = 0; rep < 4; rep++) {
        int kvp = rep * 8 + (srow >> 1);
#pragma unroll
        for (int j = 0; j < 4; j++)
          lV[c][(vd0 + j) * 32 + (kvp ^ vswz(vd0 + j))] = vw[rep][j];
      }
      __syncthreads();  // drains vmcnt: K(t) asyncs + V loads complete

      if (t + 1 < nt) {
        const int kv1 = (t + 1) * 64;
#pragma unroll
        for (int rep = 0; rep < 4; rep++)
          async16(&lK[c ^ 1][rep * 2048 + tid * 8],
                  Kbp + (size_t)(kv1 + rep * 16 + srow) * 6144 + kscol);
#pragma unroll
        for (int rep = 0; rep < 4; rep++)
          vreg[rep] = *(const short8*)(Vbp + (size_t)(kv1 + rep * 16 + srow) * 6144 + sc8);
      } else if (pass == 0) {
#pragma unroll
        for (int rep = 0; rep < 4; rep++)
          async16(&lK[c ^ 1][rep * 2048 + tid * 8],
                  Kbp + (size_t)(rep * 16 + srow) * 6144 + kscol);
#pragma unroll
        for (int rep = 0; rep < 4; rep++)
          vreg[rep] = *(const short8*)(Vbp + (size_t)(rep * 16 + srow) * 6144 + sc8);
      }

      // S^T = mfma(K, Q): lane (fr,hi) holds S[q=fr][kv = fc*16 + hi*4 + r]
      f32x4 sacc[2][4] = {};
      __builtin_amdgcn_s_setprio(1);
#pragma unroll
      for (int fc = 0; fc < 4; fc++)
#pragma unroll
        for (int ks = 0; ks < 4; ks++) {
          short8 bk = *(const short8*)(&lK[c][(fc * 16 + fr) * 128 +
                                              ((ks * 32 + fk8) ^ ((fr & 7) << 3))]);
          sacc[0][fc] = __builtin_amdgcn_mfma_f32_16x16x32_bf16(bk, qf[0][ks], sacc[0][fc], 0, 0, 0);
          sacc[1][fc] = __builtin_amdgcn_mfma_f32_16x16x32_bf16(bk, qf[1][ks], sacc[1][fc], 0, 0, 0);
        }
      __builtin_amdgcn_s_setprio(0);

      const bool diag = (t >= nt - 2);
      const int kvb = t * 64;
      unsigned int pk[2][4][2];

#pragma unroll
      for (int qsub = 0; qsub < 2; qsub++) {
        const int q = q0 + w * 32 + qsub * 16 + fr;
        float sv[4][4];
#pragma unroll
        for (int fc = 0; fc < 4; fc++)
#pragma unroll
          for (int r = 0; r < 4; r++) {
            float xx = sacc[qsub][fc][r];
            if (diag && (kvb + fc * 16 + hi4 + r > q)) xx = NEGBIG;
            sv[fc][r] = xx;
          }
        float mx = sv[0][0];
#pragma unroll
        for (int fc = 0; fc < 4; fc++)
#pragma unroll
          for (int r = 0; r < 4; r++) mx = fmaxf(mx, sv[fc][r]);
        mx = fmaxf(mx, __shfl_xor(mx, 16));
        mx = fmaxf(mx, __shfl_xor(mx, 32));
        if (__any(mx > m2[qsub] + 8.0f)) {
          float mnew = fmaxf(m2[qsub], mx);
          float alpha = exp2_hw(m2[qsub] - mnew);
          m2[qsub] = mnew;
          ls[qsub] *= alpha;
          f32x4 av;
#pragma unroll
          for (int r = 0; r < 4; r++) av[r] = __shfl(alpha, hi4 + r);
#pragma unroll
          for (int nf = 0; nf < 8; nf++) oacc[qsub][nf] *= av;
        }
        float rs = 0.f;
        float p[4][4];
#pragma unroll
        for (int fc = 0; fc < 4; fc++)
#pragma unroll
          for (int r = 0; r < 4; r++) {
            p[fc][r] = exp2_hw(sv[fc][r] - m2[qsub]);
            rs += p[fc][r];
          }
        rs += __shfl_xor(rs, 16);
        rs += __shfl_xor(rs, 32);
        ls[qsub] += rs;
#pragma unroll
        for (int fc = 0; fc < 4; fc++) {
          pk[qsub][fc][0] = cvtpk_bf16(p[fc][0], p[fc][1]);
          pk[qsub][fc][1] = cvtpk_bf16(p[fc][2], p[fc][3]);
        }
      }

      // PV
      const int src0 = fr + ((hi & 1) << 5);
      const int src1 = src0 + 16;
#pragma unroll
      for (int kvs = 0; kvs < 2; kvs++) {
        unsigned int aw[2][4];
#pragma unroll
        for (int qsub = 0; qsub < 2; qsub++) {
#pragma unroll
          for (int jj = 0; jj < 4; jj++) {
            int src = (jj < 2) ? src0 : src1;
            int rr = jj & 1;
            unsigned int y0 = (unsigned)__shfl((int)pk[qsub][kvs * 2][rr], src);
            unsigned int y1 = (unsigned)__shfl((int)pk[qsub][kvs * 2 + 1][rr], src);
            aw[qsub][jj] = (hi >> 1) ? y1 : y0;
          }
        }
        int4v a0i = {(int)aw[0][0], (int)aw[0][1], (int)aw[0][2], (int)aw[0][3]};
        int4v a1i = {(int)aw[1][0], (int)aw[1][1], (int)aw[1][2], (int)aw[1][3]};
        short8 af0 = i4_to_s8(a0i), af1 = i4_to_s8(a1i);
        __builtin_amdgcn_s_setprio(1);
#pragma unroll
        for (int nf = 0; nf < 8; nf++) {
          int row = nf * 16 + fr;
          int4v bvw = *(const int4v*)(&lV[c][row * 32 + ((kvs * 16 + hi4) ^ vswz(row))]);
          short8 bv = i4_to_s8(bvw);
          oacc[0][nf] = __builtin_amdgcn_mfma_f32_16x16x32_bf16(af0, bv, oacc[0][nf], 0, 0, 0);
          oacc[1][nf] = __builtin_amdgcn_mfma_f32_16x16x32_bf16(af1, bv, oacc[1][nf], 0, 0, 0);
        }
        __builtin_amdgcn_s_setprio(0);
      }

      packV(vreg, parity, vw);
    }

    // epilogue for this pass
#pragma unroll
    for (int qsub = 0; qsub < 2; qsub++) {
      f32x4 iv;
#pragma unroll
      for (int r = 0; r < 4; r++) iv[r] = 1.0f / __shfl(ls[qsub], hi4 + r);
#pragma unroll
      for (int r = 0; r < 4; r++) {
        unsigned short* op =
            O + (size_t)(b * 2048 + q0 + w * 32 + qsub * 16 + hi4 + r) * 4096 + h * 128 + fr;
#pragma unroll
        for (int nf = 0; nf < 8; nf++) op[nf * 16] = f2bf(oacc[qsub][nf][r] * iv[r]);
      }
    }
  }
}

// ---------------------------------------------------------------------------
extern "C" void kernel_launch(void* const* d_in, const int* in_sizes, int n_in,
                              void* d_out, int out_size, void* d_ws, size_t ws_size,
                              hipStream_t stream) {
  const float* hs = (const float*)d_in[0];
  const float* wq = (const float*)d_in[1];
  const float* wk = (const float*)d_in[2];
  const float* wv = (const float*)d_in[3];
  const float* wo = (const float*)d_in[4];
  const float* cosb = (const float*)d_in[5];
  const float* sinb = (const float*)d_in[6];
  // d_in[7] attn_mask: pure causal, applied structurally

  unsigned short* ws = (unsigned short*)d_ws;
  unsigned short* T1 = ws;              // 4096x4096 (WqT, later WoT)
  unsigned short* T2 = T1 + 16777216;   // 1024x4096 (WkT)   } contiguous =
  unsigned short* T3 = T2 + 4194304;    // 1024x4096 (WvT)   } WqkvT 6144x4096
  unsigned short* QKV = T3 + 4194304;   // 4096x6144 (Q | K | V)
  unsigned short* Ob = QKV + 25165824;  // 4096x4096

  unsigned short* hsb = (unsigned short*)d_out;  // bf16 hs (consumed pre-O-gemm)

  downcast_f2b<<<8192, 256, 0, stream>>>(hs, hsb, 2097152);
  transpose64_f2b<<<dim3(64, 64), 256, 0, stream>>>(wq, T1, 4096, 4096);
  transpose64_f2b<<<dim3(16, 64), 256, 0, stream>>>(wk, T2, 4096, 1024);
  transpose64_f2b<<<dim3(16, 64), 256, 0, stream>>>(wv, T3, 4096, 1024);

  // merged QKV projection: C (4096 x 6144) = hs @ [Wq | Wk | Wv]
  gemm8p<0><<<dim3(16, 24), 512, 0, stream>>>(hsb, T1, QKV, 4096, 6144, 4096);

  // T1 free now: stage WoT
  transpose64_f2b<<<dim3(64, 64), 256, 0, stream>>>(wo, T1, 4096, 4096);

  // RoPE on K only; Q-RoPE (+ attscale*log2e) is fused into flash_attn
  rope_k<<<1024, 256, 0, stream>>>(QKV, cosb, sinb);

  const float qscale = 0.08838834764831845f * 1.4426950408889634f;
  flash_attn<<<dim3(8, 32, 2), 256, 0, stream>>>(QKV, Ob, cosb, sinb, qscale);

  gemm8p<1><<<dim3(16, 16), 512, 0, stream>>>(Ob, T1, (float*)d_out, 4096, 4096, 4096);
}

// Round 23
// 518.622 us; speedup vs baseline: 1.0352x; 1.0173x over previous
//
#include <hip/hip_runtime.h>

typedef __attribute__((ext_vector_type(8))) short short8;
typedef __attribute__((ext_vector_type(4))) float f32x4;
typedef __attribute__((ext_vector_type(4))) int int4v;

__device__ __forceinline__ float bf2f(unsigned short u) {
  unsigned int x = ((unsigned int)u) << 16;
  float f;
  __builtin_memcpy(&f, &x, 4);
  return f;
}
__device__ __forceinline__ unsigned short f2bf(float f) {
  unsigned int x;
  __builtin_memcpy(&x, &f, 4);
  unsigned int r = (x + 0x7FFFu + ((x >> 16) & 1u)) >> 16;
  return (unsigned short)r;
}
__device__ __forceinline__ unsigned int cvtpk_bf16(float lo, float hi) {
  unsigned int r;
  asm("v_cvt_pk_bf16_f32 %0, %1, %2" : "=v"(r) : "v"(lo), "v"(hi));
  return r;
}
// hardware exp2: v_exp_f32 computes D = 2^S0
__device__ __forceinline__ float exp2_hw(float x) {
  float r;
  asm("v_exp_f32 %0, %1" : "=v"(r) : "v"(x));
  return r;
}
__device__ __forceinline__ int4v s8_to_i4(short8 v) {
  int4v r;
  __builtin_memcpy(&r, &v, 16);
  return r;
}
__device__ __forceinline__ short8 i4_to_s8(int4v v) {
  short8 r;
  __builtin_memcpy(&r, &v, 16);
  return r;
}
__device__ __forceinline__ short8 ld8_f32(const float* p) {
  f32x4 x = *(const f32x4*)p;
  f32x4 y = *(const f32x4*)(p + 4);
  short8 r;
  r[0] = (short)f2bf(x[0]); r[1] = (short)f2bf(x[1]);
  r[2] = (short)f2bf(x[2]); r[3] = (short)f2bf(x[3]);
  r[4] = (short)f2bf(y[0]); r[5] = (short)f2bf(y[1]);
  r[6] = (short)f2bf(y[2]); r[7] = (short)f2bf(y[3]);
  return r;
}

__device__ __forceinline__ void async16(unsigned short* lds, const unsigned short* g) {
  __builtin_amdgcn_global_load_lds(
      (const __attribute__((address_space(1))) void*)g,
      (__attribute__((address_space(3))) void*)lds, 16, 0, 0);
}

// ---------------------------------------------------------------------------
// Fused prologue: one dispatch covering
//   blocks [0, 8192):      hs fp32 -> bf16 downcast (8 elems/thread)
//   blocks [8192, 12288):  wq transpose+downcast (64x64 tiles, 4096 blocks)
//   blocks [12288, 13312): wk transpose+downcast (1024 blocks)
//   blocks [13312, 14336): wv transpose+downcast (1024 blocks)
// Branches are block-uniform; all outputs independent.
// ---------------------------------------------------------------------------
__global__ void prep_fused(const float* __restrict__ hs, unsigned short* __restrict__ hsb,
                           const float* __restrict__ wq, const float* __restrict__ wk,
                           const float* __restrict__ wv,
                           unsigned short* __restrict__ T1, unsigned short* __restrict__ T2,
                           unsigned short* __restrict__ T3) {
  alignas(16) __shared__ unsigned short t[64][72];
  int bid = blockIdx.x;
  const int tid = threadIdx.x;
  if (bid < 8192) {
    int i = bid * 256 + tid;  // covers exactly 4096*4096/8 elements
    *(short8*)(hsb + (size_t)i * 8) = ld8_f32(hs + (size_t)i * 8);
    return;
  }
  bid -= 8192;
  const float* in;
  unsigned short* out;
  int C, c0, r0;
  if (bid < 4096) {
    in = wq; out = T1; C = 4096;
    c0 = (bid & 63) * 64; r0 = (bid >> 6) * 64;
  } else if (bid < 5120) {
    int bb = bid - 4096;
    in = wk; out = T2; C = 1024;
    c0 = (bb & 15) * 64; r0 = (bb >> 4) * 64;
  } else {
    int bb = bid - 5120;
    in = wv; out = T3; C = 1024;
    c0 = (bb & 15) * 64; r0 = (bb >> 4) * 64;
  }
  const int R = 4096;
  const int rr = tid >> 4;
  const int cc = (tid & 15) << 2;
#pragma unroll
  for (int i = 0; i < 4; i++) {
    int r = rr + i * 16;
    f32x4 v = *(const f32x4*)(in + (size_t)(r0 + r) * C + c0 + cc);
#pragma unroll
    for (int j = 0; j < 4; j++) t[cc + j][r] = f2bf(v[j]);
  }
  __syncthreads();
  const int seg = tid & 7;
  const int cr = tid >> 3;
#pragma unroll
  for (int i = 0; i < 2; i++) {
    int c = cr + i * 32;
    short8 w2 = *(const short8*)&t[c][seg * 8];
    *(short8*)(out + (size_t)(c0 + c) * R + r0 + seg * 8) = w2;
  }
}

// ---------------------------------------------------------------------------
// Fused post-QKV-gemm: one dispatch covering
//   blocks [0, 4096):     wo transpose+downcast into T1
//   blocks [4096, 5120):  RoPE on the K region of QKV (Q-RoPE fused in flash)
// ---------------------------------------------------------------------------
__global__ void post_fused(const float* __restrict__ wo, unsigned short* __restrict__ T1,
                           unsigned short* __restrict__ qkv,
                           const float* __restrict__ cosb,
                           const float* __restrict__ sinb) {
  alignas(16) __shared__ unsigned short t[64][72];
  const int tid = threadIdx.x;
  int bid = blockIdx.x;
  if (bid >= 4096) {
    // rope_k body
    int gid = (bid - 4096) * 256 + tid;
    int dblk = gid & 7;
    int u2 = gid >> 3;
    int head = u2 & 7;
    int token = u2 >> 3;
    int s = token & 2047;
    int d0 = dblk << 3;
    unsigned short* p0 = qkv + (size_t)token * 6144 + 4096 + (head << 7) + d0;
    unsigned short* p1 = p0 + 64;
    const float* cp = cosb + s * 128 + d0;
    const float* sp = sinb + s * 128 + d0;
    short8 a = *(const short8*)p0;
    short8 bq = *(const short8*)p1;
    f32x4 c0 = *(const f32x4*)cp, c1 = *(const f32x4*)(cp + 4);
    f32x4 s0 = *(const f32x4*)sp, s1 = *(const f32x4*)(sp + 4);
    short8 o0, o1;
#pragma unroll
    for (int j = 0; j < 8; j++) {
      float x0 = bf2f((unsigned short)a[j]);
      float x1 = bf2f((unsigned short)bq[j]);
      float c = (j < 4) ? c0[j & 3] : c1[j & 3];
      float sn = (j < 4) ? s0[j & 3] : s1[j & 3];
      o0[j] = (short)f2bf(x0 * c - x1 * sn);
      o1[j] = (short)f2bf(x1 * c + x0 * sn);
    }
    *(short8*)p0 = o0;
    *(short8*)p1 = o1;
    return;
  }
  // wo transpose
  const int C = 4096, R = 4096;
  const int c0 = (bid & 63) * 64;
  const int r0 = (bid >> 6) * 64;
  const int rr = tid >> 4;
  const int cc = (tid & 15) << 2;
#pragma unroll
  for (int i = 0; i < 4; i++) {
    int r = rr + i * 16;
    f32x4 v = *(const f32x4*)(wo + (size_t)(r0 + r) * C + c0 + cc);
#pragma unroll
    for (int j = 0; j < 4; j++) t[cc + j][r] = f2bf(v[j]);
  }
  __syncthreads();
  const int seg = tid & 7;
  const int cr = tid >> 3;
#pragma unroll
  for (int i = 0; i < 2; i++) {
    int c = cr + i * 32;
    short8 w2 = *(const short8*)&t[c][seg * 8];
    *(short8*)(T1 + (size_t)(c0 + c) * R + r0 + seg * 8) = w2;
  }
}

// ---------------------------------------------------------------------------
// GEMM 256x256, BK=64, 8 waves, 8-phase schedule (m201 template). Round-14
// form (validated: conflicts 0, ~1250 TF resident).
// ---------------------------------------------------------------------------
#define MFMA16(AF, B0, B1, N0, N1)                                                   \
  _Pragma("unroll") for (int mi = 0; mi < 8; mi++) {                                 \
    acc[mi][N0] = __builtin_amdgcn_mfma_f32_16x16x32_bf16(AF[mi], B0, acc[mi][N0], 0, 0, 0); \
    acc[mi][N1] = __builtin_amdgcn_mfma_f32_16x16x32_bf16(AF[mi], B1, acc[mi][N1], 0, 0, 0); \
  }

#define STAGE8(BUF, SLOT, BASE, KOFF)                                     \
  do {                                                                    \
    async16(&lds[BUF][SLOT][tid * 8], (BASE) + (KOFF));                   \
    async16(&lds[BUF][SLOT][4096 + tid * 8], (BASE) + Kstep128 + (KOFF)); \
  } while (0)

#define BAR8 asm volatile("s_barrier" ::: "memory")

#define TILE8(CUR, UU, S0, S123, VM)                                                   \
  do {                                                                                 \
    const int kb = (UU)*64;                                                            \
    short8 af[8], b0, b1;                                                              \
    /* ph0 (k0,L) */                                                                   \
    _Pragma("unroll") for (int mi = 0; mi < 8; mi++)                                   \
        af[mi] = *(const short8*)(&lds[CUR][0][(wr * 128 + mi * 16 + fr) * 32 + fragoff]); \
    b0 = *(const short8*)(&lds[CUR][2][(wc * 64 + 0 * 16 + fr) * 32 + fragoff]);       \
    b1 = *(const short8*)(&lds[CUR][2][(wc * 64 + 1 * 16 + fr) * 32 + fragoff]);       \
    if (S0) STAGE8((CUR) ^ 1, 3, Bbase, kb + 96);                                      \
    BAR8;                                                                              \
    __builtin_amdgcn_s_setprio(1);                                                     \
    MFMA16(af, b0, b1, 0, 1);                                                          \
    __builtin_amdgcn_s_setprio(0);                                                     \
    BAR8;                                                                              \
    /* ph1 (k0,R) */                                                                   \
    b0 = *(const short8*)(&lds[CUR][2][(wc * 64 + 2 * 16 + fr) * 32 + fragoff]);       \
    b1 = *(const short8*)(&lds[CUR][2][(wc * 64 + 3 * 16 + fr) * 32 + fragoff]);       \
    if (S123) STAGE8(CUR, 0, Abase, kb + 128);                                         \
    BAR8;                                                                              \
    __builtin_amdgcn_s_setprio(1);                                                     \
    MFMA16(af, b0, b1, 2, 3);                                                          \
    __builtin_amdgcn_s_setprio(0);                                                     \
    BAR8;                                                                              \
    /* ph2 (k1,L) */                                                                   \
    _Pragma("unroll") for (int mi = 0; mi < 8; mi++)                                   \
        af[mi] = *(const short8*)(&lds[CUR][1][(wr * 128 + mi * 16 + fr) * 32 + fragoff]); \
    b0 = *(const short8*)(&lds[CUR][3][(wc * 64 + 0 * 16 + fr) * 32 + fragoff]);       \
    b1 = *(const short8*)(&lds[CUR][3][(wc * 64 + 1 * 16 + fr) * 32 + fragoff]);       \
    if (S123) STAGE8(CUR, 2, Bbase, kb + 128);                                         \
    BAR8;                                                                              \
    __builtin_amdgcn_s_setprio(1);                                                     \
    MFMA16(af, b0, b1, 0, 1);                                                          \
    __builtin_amdgcn_s_setprio(0);                                                     \
    BAR8;                                                                              \
    /* ph3 (k1,R) */                                                                   \
    b0 = *(const short8*)(&lds[CUR][3][(wc * 64 + 2 * 16 + fr) * 32 + fragoff]);       \
    b1 = *(const short8*)(&lds[CUR][3][(wc * 64 + 3 * 16 + fr) * 32 + fragoff]);       \
    if (S123) STAGE8(CUR, 1, Abase, kb + 160);                                         \
    BAR8;                                                                              \
    __builtin_amdgcn_s_setprio(1);                                                     \
    MFMA16(af, b0, b1, 2, 3);                                                          \
    __builtin_amdgcn_s_setprio(0);                                                     \
    if ((VM) == 6) {                                                                   \
      asm volatile("s_waitcnt vmcnt(6)" ::: "memory");                                 \
      __builtin_amdgcn_sched_barrier(0);                                               \
    } else if ((VM) == 0) {                                                            \
      asm volatile("s_waitcnt vmcnt(0)" ::: "memory");                                 \
      __builtin_amdgcn_sched_barrier(0);                                               \
    }                                                                                  \
    BAR8;                                                                              \
  } while (0)

template <int CF32>
__global__ __launch_bounds__(512, 2) void gemm8p(
    const unsigned short* __restrict__ A, const unsigned short* __restrict__ BT,
    void* __restrict__ Cp, int M, int N, int K) {
  alignas(16) __shared__ unsigned short lds[2][4][8192];  // 128 KB
  const int tid = threadIdx.x;
  const int l = tid & 63;
  const int wv = tid >> 6;
  const int wr = wv >> 2, wc = wv & 3;

  const int nwg = gridDim.x * gridDim.y;
  int id = blockIdx.y * gridDim.x + blockIdx.x;
  id = (id & 7) * (nwg >> 3) + (id >> 3);
  const int bm = (id % gridDim.x) * 256;
  const int bn = (id / gridDim.x) * 256;

  const int fr = l & 15, hi = l >> 4;
  const int fragoff = ((hi ^ (((fr >> 3) & 1) << 1)) << 3);
  const int srow = tid >> 2;
  const int scol = (((tid & 3) ^ (((tid >> 5) & 1) << 1)) << 3);
  const unsigned short* Abase = A + (size_t)(bm + srow) * K + scol;
  const unsigned short* Bbase = BT + (size_t)(bn + srow) * K + scol;
  const size_t Kstep128 = (size_t)128 * K;

  f32x4 acc[8][4] = {};
  const int nt = K >> 6;

  STAGE8(0, 0, Abase, 0);
  STAGE8(0, 2, Bbase, 0);
  STAGE8(0, 1, Abase, 32);
  STAGE8(0, 3, Bbase, 32);
  STAGE8(1, 0, Abase, 64);
  STAGE8(1, 2, Bbase, 64);
  STAGE8(1, 1, Abase, 96);
  asm volatile("s_waitcnt vmcnt(6)" ::: "memory");
  __builtin_amdgcn_sched_barrier(0);
  BAR8;

  int U = 0;
  for (; U + 3 < nt; U += 2) {
    TILE8(0, U, 1, 1, 6);
    TILE8(1, U + 1, 1, 1, 6);
  }
  TILE8(0, nt - 2, 1, 0, 0);
  TILE8(1, nt - 1, 0, 0, -1);

  const int er = hi << 2;
#pragma unroll
  for (int mi = 0; mi < 8; mi++) {
#pragma unroll
    for (int ni = 0; ni < 4; ni++) {
      int row = bm + wr * 128 + mi * 16 + er;
      int col = bn + wc * 64 + ni * 16 + fr;
#pragma unroll
      for (int r = 0; r < 4; r++) {
        if constexpr (CF32)
          ((float*)Cp)[(size_t)(row + r) * N + col] = acc[mi][ni][r];
        else
          ((unsigned short*)Cp)[(size_t)(row + r) * N + col] = f2bf(acc[mi][ni][r]);
      }
    }
  }
}

// ---------------------------------------------------------------------------
// Flash attention: causal, GQA. QBLK=128 (4 waves x 32 q rows), KVBLK=64.
// Paired scheduling (uniform 34 kv-iters/block, grid 8x32x2), double-buffered
// lK/lV (one barrier per tile), K staged by global_load_lds direct (swizzled
// global source), V reg-staged + shfl-packed. Q-RoPE (+ attscale*log2e)
// fused into the Q fragment load (thread-local rotate-half). exp2-domain
// softmax; defer-max rescale. launch_bounds (256,2): no spill.
// ---------------------------------------------------------------------------
#define NEGBIG -30000.0f

__device__ __forceinline__ int vswz(int d) { return (((d >> 3) ^ d) & 7) << 2; }

__device__ __forceinline__ void packV(const short8 vreg[4], int parity,
                                      unsigned int vw[4][4]) {
#pragma unroll
  for (int rep = 0; rep < 4; rep++) {
    int4v own = s8_to_i4(vreg[rep]);
    int4v oth;
#pragma unroll
    for (int q = 0; q < 4; q++) oth[q] = __shfl_xor(own[q], 16);
    unsigned int oA = parity ? (unsigned)own[2] : (unsigned)own[0];
    unsigned int oB = parity ? (unsigned)own[3] : (unsigned)own[1];
    unsigned int tA = parity ? (unsigned)oth[2] : (unsigned)oth[0];
    unsigned int tB = parity ? (unsigned)oth[3] : (unsigned)oth[1];
    unsigned int evA = parity ? tA : oA, odA = parity ? oA : tA;
    unsigned int evB = parity ? tB : oB, odB = parity ? oB : tB;
    vw[rep][0] = (evA & 0xFFFFu) | (odA << 16);
    vw[rep][1] = (evA >> 16) | (odA & 0xFFFF0000u);
    vw[rep][2] = (evB & 0xFFFFu) | (odB << 16);
    vw[rep][3] = (evB >> 16) | (odB & 0xFFFF0000u);
  }
}

__global__ __launch_bounds__(256, 2) void flash_attn(
    const unsigned short* __restrict__ QKV, unsigned short* __restrict__ O,
    const float* __restrict__ cosb, const float* __restrict__ sinb,
    float qscale) {
  alignas(16) __shared__ unsigned short lK[2][64 * 128];  // 2 x 16 KB
  alignas(16) __shared__ unsigned int lV[2][128 * 32];    // 2 x 16 KB

  const int tid = threadIdx.x;
  const int lane = tid & 63;
  const int w = tid >> 6;
  const int b = blockIdx.z;
  const int h = blockIdx.y;
  const int xa = blockIdx.x;  // 0..7
  const int kvh = h >> 2;

  const int fr = lane & 15;
  const int hi = lane >> 4;
  const int fk8 = hi << 3;
  const int hi4 = hi << 2;

  const int srow = tid >> 4;
  const int sc8 = (tid & 15) << 3;
  const int parity = srow & 1;
  const int vd0 = sc8 + (parity << 2);
  const int kscol = sc8 ^ ((srow & 7) << 3);

  const unsigned short* Kbp = QKV + (size_t)(b * 2048) * 6144 + 4096 + kvh * 128;
  const unsigned short* Vbp = Kbp + 1024;

  short8 vreg[4];
  unsigned int vw[4][4];

  // prologue: async-stage K(0) into lK[0]; load+pack V(0)
#pragma unroll
  for (int rep = 0; rep < 4; rep++)
    async16(&lK[0][rep * 2048 + tid * 8],
            Kbp + (size_t)(rep * 16 + srow) * 6144 + kscol);
#pragma unroll
  for (int rep = 0; rep < 4; rep++)
    vreg[rep] = *(const short8*)(Vbp + (size_t)(rep * 16 + srow) * 6144 + sc8);
  packV(vreg, parity, vw);

  for (int pass = 0; pass < 2; pass++) {
    const int x = pass ? (15 - xa) : xa;
    const int q0 = x * 128;
    const int nt = 2 * x + 2;

    // Q fragments with fused RoPE + qscale (thread-local rotate-half).
    short8 qf[2][4];
#pragma unroll
    for (int qsub = 0; qsub < 2; qsub++) {
      const int s = q0 + w * 32 + qsub * 16 + fr;  // token position (0..2047)
      const unsigned short* qb =
          QKV + (size_t)(b * 2048 + s) * 6144 + h * 128 + fk8;
      short8 raw[4];
#pragma unroll
      for (int ks = 0; ks < 4; ks++) raw[ks] = *(const short8*)(qb + ks * 32);
#pragma unroll
      for (int ks = 0; ks < 2; ks++) {
        const float* cp = cosb + s * 128 + ks * 32 + fk8;
        const float* sp = sinb + s * 128 + ks * 32 + fk8;
        f32x4 c0 = *(const f32x4*)cp, c1 = *(const f32x4*)(cp + 4);
        f32x4 s0 = *(const f32x4*)sp, s1 = *(const f32x4*)(sp + 4);
        short8 o0, o1;
#pragma unroll
        for (int j = 0; j < 8; j++) {
          float x0 = bf2f((unsigned short)raw[ks][j]);
          float x1 = bf2f((unsigned short)raw[ks + 2][j]);
          float c = (j < 4) ? c0[j & 3] : c1[j & 3];
          float sn = (j < 4) ? s0[j & 3] : s1[j & 3];
          o0[j] = (short)f2bf((x0 * c - x1 * sn) * qscale);
          o1[j] = (short)f2bf((x1 * c + x0 * sn) * qscale);
        }
        qf[qsub][ks] = o0;
        qf[qsub][ks + 2] = o1;
      }
    }

    f32x4 oacc[2][8] = {};
    float m2[2] = {NEGBIG, NEGBIG};
    float ls[2] = {0.f, 0.f};

    for (int t = 0; t < nt; t++) {
      const int c = t & 1;
#pragma unroll
      for (int rep = 0; rep < 4; rep++) {
        int kvp = rep * 8 + (srow >> 1);
#pragma unroll
        for (int j = 0; j < 4; j++)
          lV[c][(vd0 + j) * 32 + (kvp ^ vswz(vd0 + j))] = vw[rep][j];
      }
      __syncthreads();  // drains vmcnt: K(t) asyncs + V loads complete

      if (t + 1 < nt) {
        const int kv1 = (t + 1) * 64;
#pragma unroll
        for (int rep = 0; rep < 4; rep++)
          async16(&lK[c ^ 1][rep * 2048 + tid * 8],
                  Kbp + (size_t)(kv1 + rep * 16 + srow) * 6144 + kscol);
#pragma unroll
        for (int rep = 0; rep < 4; rep++)
          vreg[rep] = *(const short8*)(Vbp + (size_t)(kv1 + rep * 16 + srow) * 6144 + sc8);
      } else if (pass == 0) {
#pragma unroll
        for (int rep = 0; rep < 4; rep++)
          async16(&lK[c ^ 1][rep * 2048 + tid * 8],
                  Kbp + (size_t)(rep * 16 + srow) * 6144 + kscol);
#pragma unroll
        for (int rep = 0; rep < 4; rep++)
          vreg[rep] = *(const short8*)(Vbp + (size_t)(rep * 16 + srow) * 6144 + sc8);
      }

      // S^T = mfma(K, Q): lane (fr,hi) holds S[q=fr][kv = fc*16 + hi*4 + r]
      f32x4 sacc[2][4] = {};
      __builtin_amdgcn_s_setprio(1);
#pragma unroll
      for (int fc = 0; fc < 4; fc++)
#pragma unroll
        for (int ks = 0; ks < 4; ks++) {
          short8 bk = *(const short8*)(&lK[c][(fc * 16 + fr) * 128 +
                                              ((ks * 32 + fk8) ^ ((fr & 7) << 3))]);
          sacc[0][fc] = __builtin_amdgcn_mfma_f32_16x16x32_bf16(bk, qf[0][ks], sacc[0][fc], 0, 0, 0);
          sacc[1][fc] = __builtin_amdgcn_mfma_f32_16x16x32_bf16(bk, qf[1][ks], sacc[1][fc], 0, 0, 0);
        }
      __builtin_amdgcn_s_setprio(0);

      const bool diag = (t >= nt - 2);
      const int kvb = t * 64;
      unsigned int pk[2][4][2];

#pragma unroll
      for (int qsub = 0; qsub < 2; qsub++) {
        const int q = q0 + w * 32 + qsub * 16 + fr;
        float sv[4][4];
#pragma unroll
        for (int fc = 0; fc < 4; fc++)
#pragma unroll
          for (int r = 0; r < 4; r++) {
            float xx = sacc[qsub][fc][r];
            if (diag && (kvb + fc * 16 + hi4 + r > q)) xx = NEGBIG;
            sv[fc][r] = xx;
          }
        float mx = sv[0][0];
#pragma unroll
        for (int fc = 0; fc < 4; fc++)
#pragma unroll
          for (int r = 0; r < 4; r++) mx = fmaxf(mx, sv[fc][r]);
        mx = fmaxf(mx, __shfl_xor(mx, 16));
        mx = fmaxf(mx, __shfl_xor(mx, 32));
        if (__any(mx > m2[qsub] + 8.0f)) {
          float mnew = fmaxf(m2[qsub], mx);
          float alpha = exp2_hw(m2[qsub] - mnew);
          m2[qsub] = mnew;
          ls[qsub] *= alpha;
          f32x4 av;
#pragma unroll
          for (int r = 0; r < 4; r++) av[r] = __shfl(alpha, hi4 + r);
#pragma unroll
          for (int nf = 0; nf < 8; nf++) oacc[qsub][nf] *= av;
        }
        float rs = 0.f;
        float p[4][4];
#pragma unroll
        for (int fc = 0; fc < 4; fc++)
#pragma unroll
          for (int r = 0; r < 4; r++) {
            p[fc][r] = exp2_hw(sv[fc][r] - m2[qsub]);
            rs += p[fc][r];
          }
        rs += __shfl_xor(rs, 16);
        rs += __shfl_xor(rs, 32);
        ls[qsub] += rs;
#pragma unroll
        for (int fc = 0; fc < 4; fc++) {
          pk[qsub][fc][0] = cvtpk_bf16(p[fc][0], p[fc][1]);
          pk[qsub][fc][1] = cvtpk_bf16(p[fc][2], p[fc][3]);
        }
      }

      // PV
      const int src0 = fr + ((hi & 1) << 5);
      const int src1 = src0 + 16;
#pragma unroll
      for (int kvs = 0; kvs < 2; kvs++) {
        unsigned int aw[2][4];
#pragma unroll
        for (int qsub = 0; qsub < 2; qsub++) {
#pragma unroll
          for (int jj = 0; jj < 4; jj++) {
            int src = (jj < 2) ? src0 : src1;
            int rr = jj & 1;
            unsigned int y0 = (unsigned)__shfl((int)pk[qsub][kvs * 2][rr], src);
            unsigned int y1 = (unsigned)__shfl((int)pk[qsub][kvs * 2 + 1][rr], src);
            aw[qsub][jj] = (hi >> 1) ? y1 : y0;
          }
        }
        int4v a0i = {(int)aw[0][0], (int)aw[0][1], (int)aw[0][2], (int)aw[0][3]};
        int4v a1i = {(int)aw[1][0], (int)aw[1][1], (int)aw[1][2], (int)aw[1][3]};
        short8 af0 = i4_to_s8(a0i), af1 = i4_to_s8(a1i);
        __builtin_amdgcn_s_setprio(1);
#pragma unroll
        for (int nf = 0; nf < 8; nf++) {
          int row = nf * 16 + fr;
          int4v bvw = *(const int4v*)(&lV[c][row * 32 + ((kvs * 16 + hi4) ^ vswz(row))]);
          short8 bv = i4_to_s8(bvw);
          oacc[0][nf] = __builtin_amdgcn_mfma_f32_16x16x32_bf16(af0, bv, oacc[0][nf], 0, 0, 0);
          oacc[1][nf] = __builtin_amdgcn_mfma_f32_16x16x32_bf16(af1, bv, oacc[1][nf], 0, 0, 0);
        }
        __builtin_amdgcn_s_setprio(0);
      }

      packV(vreg, parity, vw);
    }

    // epilogue for this pass
#pragma unroll
    for (int qsub = 0; qsub < 2; qsub++) {
      f32x4 iv;
#pragma unroll
      for (int r = 0; r < 4; r++) iv[r] = 1.0f / __shfl(ls[qsub], hi4 + r);
#pragma unroll
      for (int r = 0; r < 4; r++) {
        unsigned short* op =
            O + (size_t)(b * 2048 + q0 + w * 32 + qsub * 16 + hi4 + r) * 4096 + h * 128 + fr;
#pragma unroll
        for (int nf = 0; nf < 8; nf++) op[nf * 16] = f2bf(oacc[qsub][nf][r] * iv[r]);
      }
    }
  }
}

// ---------------------------------------------------------------------------
extern "C" void kernel_launch(void* const* d_in, const int* in_sizes, int n_in,
                              void* d_out, int out_size, void* d_ws, size_t ws_size,
                              hipStream_t stream) {
  const float* hs = (const float*)d_in[0];
  const float* wq = (const float*)d_in[1];
  const float* wk = (const float*)d_in[2];
  const float* wv = (const float*)d_in[3];
  const float* wo = (const float*)d_in[4];
  const float* cosb = (const float*)d_in[5];
  const float* sinb = (const float*)d_in[6];
  // d_in[7] attn_mask: pure causal, applied structurally

  unsigned short* ws = (unsigned short*)d_ws;
  unsigned short* T1 = ws;              // 4096x4096 (WqT, later WoT)
  unsigned short* T2 = T1 + 16777216;   // 1024x4096 (WkT)   } contiguous =
  unsigned short* T3 = T2 + 4194304;    // 1024x4096 (WvT)   } WqkvT 6144x4096
  unsigned short* QKV = T3 + 4194304;   // 4096x6144 (Q | K | V)
  unsigned short* Ob = QKV + 25165824;  // 4096x4096

  unsigned short* hsb = (unsigned short*)d_out;  // bf16 hs (consumed pre-O-gemm)

  // fused prologue: downcast + wq/wk/wv transposes (one dispatch)
  prep_fused<<<14336, 256, 0, stream>>>(hs, hsb, wq, wk, wv, T1, T2, T3);

  // merged QKV projection: C (4096 x 6144) = hs @ [Wq | Wk | Wv]
  gemm8p<0><<<dim3(16, 24), 512, 0, stream>>>(hsb, T1, QKV, 4096, 6144, 4096);

  // fused post: wo transpose into T1 + RoPE on K region (one dispatch)
  post_fused<<<5120, 256, 0, stream>>>(wo, T1, QKV, cosb, sinb);

  const float qscale = 0.08838834764831845f * 1.4426950408889634f;
  flash_attn<<<dim3(8, 32, 2), 256, 0, stream>>>(QKV, Ob, cosb, sinb, qscale);

  gemm8p<1><<<dim3(16, 16), 512, 0, stream>>>(Ob, T1, (float*)d_out, 4096, 4096, 4096);
}